// Round 12
// baseline (3665.862 us; speedup 1.0000x reference)
//
#include <hip/hip_runtime.h>
#include <math.h>

// ---------------- problem constants ----------------
constexpr int Bc = 32, Cch = 3, Hh = 224, Ww = 224, Pp = 16;
constexpr int Dd = 768, NH = 12, DHd = 64, INNERc = 768;
constexpr int DEPTHc = 12, NCLS = 1000;
constexpr int NPc = 196, Nn = 197, PD = 768;
constexpr float EPSf = 1e-5f;

typedef _Float16 half_t;
typedef __attribute__((ext_vector_type(8))) _Float16 half8;
typedef __attribute__((ext_vector_type(4))) float f32x4;
typedef __attribute__((ext_vector_type(4))) unsigned int uint32x4;

// ---------------- reduction helpers ----------------
__device__ __forceinline__ float wave_red_sum(float v) {
#pragma unroll
    for (int m = 32; m; m >>= 1) v += __shfl_xor(v, m);
    return v;
}

__device__ __forceinline__ void block_red2(float& s, float& s2, float* red) {
    s = wave_red_sum(s);
    s2 = wave_red_sum(s2);
    int wid = threadIdx.x >> 6, lane = threadIdx.x & 63;
    if (lane == 0) { red[wid] = s; red[4 + wid] = s2; }
    __syncthreads();
    s = red[0] + red[1] + red[2] + red[3];
    s2 = red[4] + red[5] + red[6] + red[7];
}

// ---------------- patchify + patch LN -> f16 ----------------
__global__ __launch_bounds__(256) void k_patch_ln(
        const float* __restrict__ img, const float* __restrict__ g,
        const float* __restrict__ bb, half_t* __restrict__ out) {
    int pid = blockIdx.x;
    int b = pid / NPc, n = pid % NPc;
    int ph = n / 14, pw = n % 14;
    int t = threadIdx.x;
    __shared__ float red[8];
    float v[3];
#pragma unroll
    for (int i = 0; i < 3; i++) {
        int d = t + i * 256;
        int c = d % 3, q = (d / 3) & 15, p = d / 48;
        v[i] = img[((long)(b * Cch + c) * Hh + ph * Pp + p) * Ww + pw * Pp + q];
    }
    float s = v[0] + v[1] + v[2];
    float s2 = v[0] * v[0] + v[1] * v[1] + v[2] * v[2];
    block_red2(s, s2, red);
    float mu = s * (1.f / PD);
    float var = s2 * (1.f / PD) - mu * mu;
    float r = rsqrtf(var + EPSf);
#pragma unroll
    for (int i = 0; i < 3; i++) {
        int d = t + i * 256;
        out[(long)pid * PD + d] = (half_t)((v[i] - mu) * r * g[d] + bb[d]);
    }
}

// ---------------- row LayerNorm (768 wide), templated output ----------------
template <typename T>
__global__ __launch_bounds__(256) void k_ln(
        const float* __restrict__ in, const float* __restrict__ g,
        const float* __restrict__ bb, T* __restrict__ out,
        long in_stride, long out_stride) {
    long row = blockIdx.x;
    const float* ip = in + row * in_stride;
    T* op = out + row * out_stride;
    int t = threadIdx.x;
    __shared__ float red[8];
    float v[3];
#pragma unroll
    for (int i = 0; i < 3; i++) v[i] = ip[t + i * 256];
    float s = v[0] + v[1] + v[2];
    float s2 = v[0] * v[0] + v[1] * v[1] + v[2] * v[2];
    block_red2(s, s2, red);
    float mu = s * (1.f / Dd);
    float var = s2 * (1.f / Dd) - mu * mu;
    float r = rsqrtf(var + EPSf);
#pragma unroll
    for (int i = 0; i < 3; i++) {
        int d = t + i * 256;
        op[d] = (T)((v[i] - mu) * r * g[d] + bb[d]);
    }
}

// ---------------- embed assemble: LN(tmp)+pos, cls+pos ----------------
__global__ __launch_bounds__(256) void k_embed(
        const float* __restrict__ tmp, const float* __restrict__ cls,
        const float* __restrict__ pos, const float* __restrict__ g,
        const float* __restrict__ bb, float* __restrict__ x) {
    int pid = blockIdx.x;
    int b = pid / Nn, n = pid % Nn;
    int t = threadIdx.x;
    float* xp = x + (long)pid * Dd;
    if (n == 0) {
#pragma unroll
        for (int i = 0; i < 3; i++) {
            int d = t + i * 256;
            xp[d] = cls[d] + pos[d];
        }
        return;
    }
    const float* ip = tmp + (long)(b * NPc + n - 1) * Dd;
    __shared__ float red[8];
    float v[3];
#pragma unroll
    for (int i = 0; i < 3; i++) v[i] = ip[t + i * 256];
    float s = v[0] + v[1] + v[2];
    float s2 = v[0] * v[0] + v[1] * v[1] + v[2] * v[2];
    block_red2(s, s2, red);
    float mu = s * (1.f / Dd);
    float var = s2 * (1.f / Dd) - mu * mu;
    float r = rsqrtf(var + EPSf);
#pragma unroll
    for (int i = 0; i < 3; i++) {
        int d = t + i * 256;
        xp[d] = (v[i] - mu) * r * g[d] + bb[d] + pos[(long)n * Dd + d];
    }
}

// ---------------- weight prep: fp32 W[K][N] -> f16 Wt[N][K] ----------------
__global__ __launch_bounds__(256) void k_wprep(
        const float* __restrict__ W, half_t* __restrict__ Wt, int K, int N) {
    W += (long)blockIdx.z * K * N;
    Wt += (long)blockIdx.z * K * N;
    __shared__ float tile[32][33];
    int n = blockIdx.x * 32 + threadIdx.x;
    int k0 = blockIdx.y * 32;
#pragma unroll
    for (int i = 0; i < 4; i++)
        tile[threadIdx.y + i * 8][threadIdx.x] = W[(long)(k0 + threadIdx.y + i * 8) * N + n];
    __syncthreads();
    int kk = k0 + threadIdx.x;
#pragma unroll
    for (int i = 0; i < 4; i++)
        Wt[(long)(blockIdx.x * 32 + threadIdx.y + i * 8) * K + kk] =
            (half_t)tile[threadIdx.x][threadIdx.y + i * 8];
}

// ---------------- head weight prep: fp32 [768][1000] -> f16 [1024][768] (pad 0) --------
__global__ __launch_bounds__(256) void k_wprep_head(
        const float* __restrict__ W, half_t* __restrict__ Wt) {
    __shared__ float tile[32][33];
    int n = blockIdx.x * 32 + threadIdx.x;
    int k0 = blockIdx.y * 32;
#pragma unroll
    for (int i = 0; i < 4; i++)
        tile[threadIdx.y + i * 8][threadIdx.x] =
            (n < NCLS) ? W[(long)(k0 + threadIdx.y + i * 8) * NCLS + n] : 0.f;
    __syncthreads();
    int kk = k0 + threadIdx.x;
#pragma unroll
    for (int i = 0; i < 4; i++)
        Wt[(long)(blockIdx.x * 32 + threadIdx.y + i * 8) * Dd + kk] =
            (half_t)tile[threadIdx.x][threadIdx.y + i * 8];
}

// ---------------- head GEMM: one thread per (row,col), f16 dot ----------------
__global__ __launch_bounds__(256) void k_head(
        const half_t* __restrict__ Ah, const half_t* __restrict__ Wh,
        const float* __restrict__ bias, float* __restrict__ out) {
    int idx = blockIdx.x * 256 + threadIdx.x;
    int row = idx >> 10, col = idx & 1023;
    if (col >= NCLS) return;
    const half_t* ap = Ah + (long)row * Dd;
    const half_t* wp = Wh + (long)col * Dd;
    float acc = 0.f;
#pragma unroll
    for (int k = 0; k < 96; k++) {
        half8 a = *(const half8*)&ap[k * 8];
        half8 w = *(const half8*)&wp[k * 8];
#pragma unroll
        for (int u = 0; u < 8; u++) acc += (float)a[u] * (float)w[u];
    }
    out[(long)row * NCLS + col] = acc + bias[col];
}

// ---------------- f16 MFMA GEMM ----------------
// OMODE=1 (qkv): C=q, C1=k head-major [b,h,n,64]; V third (n0>=1536) staged
//   TRANSPOSED in LDS then written lane-coalesced into Vt [b,h,64,224].
__device__ __forceinline__ half8 lds_frag(const uint32x4 (*L)[8], int row, int slot) {
    union { uint32x4 u; half8 h; } t;
    t.u = L[row][slot];
    return t.h;
}

template <int HASB, int HASR, typename CT, int OMODE>
__global__ __launch_bounds__(256, 2) void k_hgemm(
        const half_t* __restrict__ A, const half_t* __restrict__ Bt,
        const float* __restrict__ bias, const float* __restrict__ res,
        CT* __restrict__ C, CT* __restrict__ C1, half_t* __restrict__ Vt,
        int M, int N, int K) {
    __shared__ uint32x4 smem[2176];
    uint32x4 (*As)[8] = (uint32x4(*)[8])smem;
    uint32x4 (*Bs)[8] = (uint32x4(*)[8])(smem + 1024);
    const int tid = threadIdx.x;
    const int nwg = gridDim.x;
    const int q8 = nwg >> 3, r8 = nwg & 7;
    const int xc = blockIdx.x & 7, oo = blockIdx.x >> 3;
    const int tile = (xc < r8 ? xc * (q8 + 1) : r8 * (q8 + 1) + (xc - r8) * q8) + oo;
    const int gx = N >> 7;
    const int n0 = (tile % gx) * 128, m0 = (tile / gx) * 128;
    const int lane = tid & 63, w = tid >> 6;
    const int wrr = (w >> 1) * 64, wcc = (w & 1) * 64;
    const int lrow = lane & 15, lgrp = lane >> 4;

    int lm[4], sw[4];
    long gA[4], gB[4];
    const int cb = (tid & 7) * 8;
#pragma unroll
    for (int c = 0; c < 4; ++c) {
        lm[c] = c * 32 + (tid >> 3);
        sw[c] = (tid & 7) ^ (lm[c] & 7);
        int ma = m0 + lm[c];
        if (ma > M - 1) ma = M - 1;
        gA[c] = (long)ma * K + cb;
        gB[c] = (long)(n0 + lm[c]) * K + cb;
    }

    f32x4 acc[4][4] = {};
    uint32x4 ra[4], rb[4];
#pragma unroll
    for (int c = 0; c < 4; ++c) { ra[c] = *(const uint32x4*)(A + gA[c]); rb[c] = *(const uint32x4*)(Bt + gB[c]); }
#pragma unroll
    for (int c = 0; c < 4; ++c) { As[lm[c]][sw[c]] = ra[c]; Bs[lm[c]][sw[c]] = rb[c]; }
    __syncthreads();

    const int nst = K >> 6;
    for (int t = 0; t < nst; ++t) {
        if (t + 1 < nst) {
            const int k0 = (t + 1) << 6;
#pragma unroll
            for (int c = 0; c < 4; ++c) {
                ra[c] = *(const uint32x4*)(A + gA[c] + k0);
                rb[c] = *(const uint32x4*)(Bt + gB[c] + k0);
            }
        }
#pragma unroll
        for (int kh = 0; kh < 2; ++kh) {
            half8 af[4], bf[4];
#pragma unroll
            for (int i2 = 0; i2 < 4; ++i2) {
                int m = wrr + i2 * 16 + lrow;
                af[i2] = lds_frag(As, m, (kh * 4 + lgrp) ^ (m & 7));
                int n = wcc + i2 * 16 + lrow;
                bf[i2] = lds_frag(Bs, n, (kh * 4 + lgrp) ^ (n & 7));
            }
#pragma unroll
            for (int i2 = 0; i2 < 4; ++i2)
#pragma unroll
                for (int j2 = 0; j2 < 4; ++j2)
                    acc[i2][j2] = __builtin_amdgcn_mfma_f32_16x16x32_f16(af[i2], bf[j2], acc[i2][j2], 0, 0, 0);
        }
        if (t + 1 < nst) {
            __syncthreads();
#pragma unroll
            for (int c = 0; c < 4; ++c) { As[lm[c]][sw[c]] = ra[c]; Bs[lm[c]][sw[c]] = rb[c]; }
            __syncthreads();
        }
    }

    if constexpr (sizeof(CT) == 2) {
        if constexpr (OMODE == 1) {
            if (n0 >= 1536) {
                // V third: stage TRANSPOSED in LDS (Cs[col][token], stride 136),
                // then lane-coalesced scalar stores (consecutive lanes = consecutive nn).
                __syncthreads();
                half_t* Cs = (half_t*)smem;
#pragma unroll
                for (int i2 = 0; i2 < 4; ++i2)
#pragma unroll
                    for (int j2 = 0; j2 < 4; ++j2) {
                        int colc = wcc + j2 * 16 + lrow;
#pragma unroll
                        for (int q = 0; q < 4; ++q) {
                            int r = wrr + i2 * 16 + lgrp * 4 + q;
                            Cs[colc * 136 + r] = (half_t)acc[i2][j2][q];
                        }
                    }
                __syncthreads();
                const int rr = tid & 127;      // token offset (lane-consecutive)
                const int cbase = (tid >> 7) * 64;
                int token = m0 + rr;
                bool ok = token < M;
                int b = 0, nn = 0;
                if (ok) { b = token / Nn; nn = token - b * Nn; }
#pragma unroll
                for (int cc = 0; cc < 64; ++cc) {
                    int c = cbase + cc;
                    int rem = n0 + c - 1536;
                    int h = rem >> 6, d = rem & 63;
                    if (ok)
                        Vt[((long)(b * NH + h) * 64 + d) * 224 + nn] = Cs[c * 136 + rr];
                }
                return;
            }
        }
        __syncthreads();
        half_t* Cs = (half_t*)smem;
#pragma unroll
        for (int i2 = 0; i2 < 4; ++i2)
#pragma unroll
            for (int j2 = 0; j2 < 4; ++j2) {
                int colc = wcc + j2 * 16 + lrow;
                float bv = HASB ? bias[n0 + colc] : 0.f;
#pragma unroll
                for (int q = 0; q < 4; ++q) {
                    int r = wrr + i2 * 16 + lgrp * 4 + q;
                    Cs[r * 136 + colc] = (half_t)(acc[i2][j2][q] + bv);
                }
            }
        __syncthreads();
#pragma unroll
        for (int it = 0; it < 8; ++it) {
            int idx = tid + it * 256;
            int row = idx >> 4, cu = idx & 15;
            int token = m0 + row;
            if (token < M) {
                uint32x4 val = *(const uint32x4*)(Cs + row * 136 + cu * 8);
                if constexpr (OMODE == 1) {
                    int gc = n0 + cu * 8;
                    int which = gc >= 768 ? 1 : 0;
                    int rem = gc - which * 768;
                    int h = rem >> 6, d = rem & 63;
                    int b = token / Nn, nn = token - b * Nn;
                    CT* dst = (which == 0 ? C : C1);
                    __builtin_nontemporal_store(val,
                        (uint32x4*)(dst + (((long)(b * NH + h) * Nn + nn) << 6) + d));
                } else {
                    __builtin_nontemporal_store(val,
                        (uint32x4*)(C + (long)token * N + n0 + cu * 8));
                }
            }
        }
    } else {
#pragma unroll
        for (int i2 = 0; i2 < 4; ++i2)
#pragma unroll
            for (int j2 = 0; j2 < 4; ++j2) {
                int colc = n0 + wcc + j2 * 16 + lrow;
                float bv = HASB ? bias[colc] : 0.f;
#pragma unroll
                for (int q = 0; q < 4; ++q) {
                    int r = m0 + wrr + i2 * 16 + lgrp * 4 + q;
                    if (r < M) {
                        float v = acc[i2][j2][q] + bv;
                        if (HASR) v += res[(long)r * N + colc];
                        __builtin_nontemporal_store(v, &C[(long)r * N + colc]);
                    }
                }
            }
    }
}

// ---------------- merged attention: QK^T once + cross-head z-score + softmax + PV -----
// Block per (b, i-tile16), 12 waves = 12 heads. S kept in registers (ez);
// cross-head sums via LDS f32 atomics; PV through wave-private 64-col LDS phases.
__global__ __launch_bounds__(768, 1) void k_attn3(
        const half_t* __restrict__ qh, const half_t* __restrict__ kh,
        const half_t* __restrict__ vt, half_t* __restrict__ o) {
    __shared__ float muB[16][208];        // sum -> mu
    __shared__ float rsB[16][208];        // sumsq -> rsqrt(var)
    __shared__ half_t PB[12][16][72];     // per-wave P phase buffer (64 cols + pad)
    const int tid = threadIdx.x;
    // bijective XCD swizzle: 416 = 8*52
    const int tile = (blockIdx.x & 7) * 52 + (blockIdx.x >> 3);
    const int b = tile / 13, it = tile % 13;
    const int i0 = it * 16;
    const int w = tid >> 6, lane = tid & 63;   // w = head
    const int lrow = lane & 15, lg = lane >> 4;
    const long bh = (long)(b * NH + w);

    for (int idx = tid; idx < 16 * 208; idx += 768) {
        (&muB[0][0])[idx] = 0.f;
        (&rsB[0][0])[idx] = 0.f;
    }
    __syncthreads();

    const int arow = min(i0 + lrow, Nn - 1);
    const half_t* Qp = qh + bh * Nn * 64;
    const half_t* Kp = kh + bh * Nn * 64;
    half8 af0 = *(const half8*)&Qp[(long)arow * 64 + lg * 8];
    half8 af1 = *(const half8*)&Qp[(long)arow * 64 + 32 + lg * 8];

    // ---- QK^T once; S kept in ez; sums to LDS ----
    float ez[13][4];
#pragma unroll
    for (int jt = 0; jt < 13; jt++) {
        int jr = min(jt * 16 + lrow, Nn - 1);
        half8 bf0 = *(const half8*)&Kp[(long)jr * 64 + lg * 8];
        half8 bf1 = *(const half8*)&Kp[(long)jr * 64 + 32 + lg * 8];
        f32x4 acc = {};
        acc = __builtin_amdgcn_mfma_f32_16x16x32_f16(af0, bf0, acc, 0, 0, 0);
        acc = __builtin_amdgcn_mfma_f32_16x16x32_f16(af1, bf1, acc, 0, 0, 0);
        int j = jt * 16 + lrow;
#pragma unroll
        for (int q = 0; q < 4; q++) {
            float s = acc[q];
            ez[jt][q] = s;
            atomicAdd(&muB[lg * 4 + q][j], s);
            atomicAdd(&rsB[lg * 4 + q][j], s * s);
        }
    }
    __syncthreads();
    for (int idx = tid; idx < 16 * 208; idx += 768) {
        float s = (&muB[0][0])[idx], s2 = (&rsB[0][0])[idx];
        float mu = s * (1.f / NH);
        float var = (s2 - s * mu) * (1.f / (NH - 1));
        (&muB[0][0])[idx] = mu;
        (&rsB[0][0])[idx] = rsqrtf(var);
    }
    __syncthreads();

    // ---- z-score + softmax (register-resident) ----
    float mx[4] = {-1e30f, -1e30f, -1e30f, -1e30f};
#pragma unroll
    for (int jt = 0; jt < 13; jt++) {
        int j = jt * 16 + lrow;
        bool joob = j > Nn - 1;
#pragma unroll
        for (int q = 0; q < 4; q++) {
            int r = lg * 4 + q;
            float z = (ez[jt][q] - muB[r][j]) * rsB[r][j];
            if (joob) z = -1e30f;
            ez[jt][q] = z;
            mx[q] = fmaxf(mx[q], z);
        }
    }
#pragma unroll
    for (int st = 1; st <= 8; st <<= 1)
#pragma unroll
        for (int q = 0; q < 4; q++) mx[q] = fmaxf(mx[q], __shfl_xor(mx[q], st));
    float sm[4] = {0.f, 0.f, 0.f, 0.f};
#pragma unroll
    for (int jt = 0; jt < 13; jt++)
#pragma unroll
        for (int q = 0; q < 4; q++) {
            float e = __expf(ez[jt][q] - mx[q]);
            ez[jt][q] = e;
            sm[q] += e;
        }
#pragma unroll
    for (int st = 1; st <= 8; st <<= 1)
#pragma unroll
        for (int q = 0; q < 4; q++) sm[q] += __shfl_xor(sm[q], st);
    float inv[4];
#pragma unroll
    for (int q = 0; q < 4; q++) inv[q] = 1.f / sm[q];

    // ---- PV in 4 phases of 64 cols (wave-private PB; DS in-order per wave) ----
    const half_t* Vtp = vt + (bh * 64) * 224;
    f32x4 oacc[4] = {};
#pragma unroll
    for (int ph = 0; ph < 4; ph++) {
        const int jt0 = ph * 4;
        const int njt = (ph == 3) ? 1 : 4;
#pragma unroll
        for (int jj = 0; jj < njt; jj++)
#pragma unroll
            for (int q = 0; q < 4; q++)
                PB[w][lg * 4 + q][jj * 16 + lrow] = (half_t)(ez[jt0 + jj][q] * inv[q]);
        if (ph == 3) {
#pragma unroll
            for (int q = 0; q < 4; q++)
                PB[w][lg * 4 + q][16 + lrow] = (half_t)0.f;   // cols 208..223 pad
        }
        const int nkt = (ph == 3) ? 1 : 2;
#pragma unroll
        for (int dt = 0; dt < 4; dt++) {
#pragma unroll
            for (int kk = 0; kk < 2; kk++) {
                if (kk >= nkt) continue;
                half8 pa = *(const half8*)&PB[w][lrow][kk * 32 + lg * 8];
                half8 vb = *(const half8*)&Vtp[(long)(dt * 16 + lrow) * 224 + (ph * 2 + kk) * 32 + lg * 8];
                oacc[dt] = __builtin_amdgcn_mfma_f32_16x16x32_f16(pa, vb, oacc[dt], 0, 0, 0);
            }
        }
    }
#pragma unroll
    for (int dt = 0; dt < 4; dt++)
#pragma unroll
        for (int q = 0; q < 4; q++) {
            int i = i0 + lg * 4 + q;
            if (i < Nn)
                o[((long)(b * Nn) + i) * INNERc + w * 64 + dt * 16 + lrow] = (half_t)oacc[dt][q];
        }
}

// ---------------- host launcher ----------------
extern "C" void kernel_launch(void* const* d_in, const int* in_sizes, int n_in,
                              void* d_out, int out_size, void* d_ws, size_t ws_size,
                              hipStream_t stream) {
    const float* img     = (const float*)d_in[0];
    const float* patch_g = (const float*)d_in[2];
    const float* patch_b = (const float*)d_in[3];
    const float* W_patch = (const float*)d_in[4];
    const float* b_patch = (const float*)d_in[5];
    const float* emb_g   = (const float*)d_in[6];
    const float* emb_b   = (const float*)d_in[7];
    const float* pos     = (const float*)d_in[8];
    const float* cls     = (const float*)d_in[9];
    const float* ln_g    = (const float*)d_in[10];
    const float* ln_b    = (const float*)d_in[11];
    const float* W_qkv   = (const float*)d_in[12];
    const float* W_out   = (const float*)d_in[13];
    const float* b_out   = (const float*)d_in[14];
    const float* fin_g   = (const float*)d_in[15];
    const float* fin_b   = (const float*)d_in[16];
    const float* W_head  = (const float*)d_in[17];
    const float* b_head  = (const float*)d_in[18];
    float* out = (float*)d_out;

    const long SZ_XD  = (long)Bc * Nn * Dd;            // 4,841,472
    const long SZ_HD  = (long)Bc * NH * Nn * DHd;      // 4,841,472
    const long SZ_VT  = (long)Bc * NH * 64 * 224;      // 5,505,024
    const long SZ_TMP = (long)Bc * NPc * Dd;

    float* x    = (float*)d_ws;
    float* tmp  = x + SZ_XD;
    half_t* xh       = (half_t*)(tmp + SZ_TMP);
    half_t* qhb      = xh + SZ_XD;
    half_t* khb      = qhb + SZ_HD;
    half_t* vtb      = khb + SZ_HD;
    half_t* clsh     = vtb + SZ_VT;                         // 32x768 f16
    half_t* wh_head  = clsh + 32 * Dd;                      // 1024x768 f16
    half_t* wt_patch = wh_head + 1024 * Dd;
    half_t* wt_qkv   = wt_patch + (long)Dd * Dd;
    half_t* wt_out   = wt_qkv + (long)DEPTHc * 3 * INNERc * Dd;

    // ---- weight prep ----
    hipLaunchKernelGGL(k_wprep, dim3(Dd / 32, Dd / 32, 1), dim3(32, 8), 0, stream,
                       W_patch, wt_patch, Dd, Dd);
    hipLaunchKernelGGL(k_wprep, dim3(3 * INNERc / 32, Dd / 32, DEPTHc), dim3(32, 8), 0, stream,
                       W_qkv, wt_qkv, Dd, 3 * INNERc);
    hipLaunchKernelGGL(k_wprep, dim3(Dd / 32, Dd / 32, DEPTHc), dim3(32, 8), 0, stream,
                       W_out, wt_out, Dd, Dd);
    hipLaunchKernelGGL(k_wprep_head, dim3(32, 24), dim3(32, 8), 0, stream,
                       W_head, wh_head);

    // 1. patchify + patch LN -> xh (f16)
    hipLaunchKernelGGL(k_patch_ln, dim3(Bc * NPc), dim3(256), 0, stream,
                       img, patch_g, patch_b, xh);
    // 2. patch GEMM (+b_patch) -> tmp fp32
    hipLaunchKernelGGL((k_hgemm<1, 0, float, 0>), dim3(6 * 49), dim3(256), 0, stream,
                       xh, wt_patch, b_patch, nullptr,
                       tmp, nullptr, nullptr, Bc * NPc, Dd, Dd);
    // 3. emb LN + cls concat + pos add -> x
    hipLaunchKernelGGL(k_embed, dim3(Bc * Nn), dim3(256), 0, stream,
                       tmp, cls, pos, emb_g, emb_b, x);

    const int Mrows = Bc * Nn;  // 6304
    for (int l = 0; l < DEPTHc; l++) {
        const float* g  = ln_g + (long)l * Dd;
        const float* bb = ln_b + (long)l * Dd;
        const half_t* Wq = wt_qkv + (long)l * 3 * INNERc * Dd;
        const half_t* Wo = wt_out + (long)l * Dd * Dd;
        const float* bo = b_out + (long)l * Dd;
        hipLaunchKernelGGL((k_ln<half_t>), dim3(Mrows), dim3(256), 0, stream,
                           x, g, bb, xh, (long)Dd, (long)Dd);
        // qkv GEMM; q/k head-major, V staged in LDS + written transposed coalesced
        hipLaunchKernelGGL((k_hgemm<0, 0, half_t, 1>), dim3(18 * 50), dim3(256), 0, stream,
                           xh, Wq, nullptr, nullptr,
                           qhb, khb, vtb, Mrows, 3 * INNERc, Dd);
        // merged attention (stats + softmax + PV)
        hipLaunchKernelGGL(k_attn3, dim3(416), dim3(768), 0, stream,
                           qhb, khb, vtb, xh);
        hipLaunchKernelGGL((k_hgemm<1, 1, float, 0>), dim3(6 * 50), dim3(256), 0, stream,
                           xh, Wo, bo, x,
                           x, nullptr, nullptr, Mrows, Dd, Dd);
    }
    // final LN (cls rows only) -> clsh f16
    hipLaunchKernelGGL((k_ln<half_t>), dim3(Bc), dim3(256), 0, stream,
                       x, fin_g, fin_b, clsh, (long)Nn * Dd, (long)Dd);
    // head GEMM: f16 dot per (row,col)
    hipLaunchKernelGGL(k_head, dim3(128), dim3(256), 0, stream,
                       clsh, wh_head, b_head, out);
}

// Round 13
// 1767.806 us; speedup vs baseline: 2.0737x; 2.0737x over previous
//
#include <hip/hip_runtime.h>
#include <math.h>

// ---------------- problem constants ----------------
constexpr int Bc = 32, Cch = 3, Hh = 224, Ww = 224, Pp = 16;
constexpr int Dd = 768, NH = 12, DHd = 64, INNERc = 768;
constexpr int DEPTHc = 12, NCLS = 1000;
constexpr int NPc = 196, Nn = 197, PD = 768;
constexpr float EPSf = 1e-5f;

typedef _Float16 half_t;
typedef __attribute__((ext_vector_type(8))) _Float16 half8;
typedef __attribute__((ext_vector_type(4))) float f32x4;
typedef __attribute__((ext_vector_type(4))) unsigned int uint32x4;

// ---------------- reduction helpers ----------------
__device__ __forceinline__ float wave_red_sum(float v) {
#pragma unroll
    for (int m = 32; m; m >>= 1) v += __shfl_xor(v, m);
    return v;
}

__device__ __forceinline__ void block_red2(float& s, float& s2, float* red) {
    s = wave_red_sum(s);
    s2 = wave_red_sum(s2);
    int wid = threadIdx.x >> 6, lane = threadIdx.x & 63;
    if (lane == 0) { red[wid] = s; red[4 + wid] = s2; }
    __syncthreads();
    s = red[0] + red[1] + red[2] + red[3];
    s2 = red[4] + red[5] + red[6] + red[7];
}

// ---------------- patchify + patch LN -> f16 ----------------
__global__ __launch_bounds__(256) void k_patch_ln(
        const float* __restrict__ img, const float* __restrict__ g,
        const float* __restrict__ bb, half_t* __restrict__ out) {
    int pid = blockIdx.x;
    int b = pid / NPc, n = pid % NPc;
    int ph = n / 14, pw = n % 14;
    int t = threadIdx.x;
    __shared__ float red[8];
    float v[3];
#pragma unroll
    for (int i = 0; i < 3; i++) {
        int d = t + i * 256;
        int c = d % 3, q = (d / 3) & 15, p = d / 48;
        v[i] = img[((long)(b * Cch + c) * Hh + ph * Pp + p) * Ww + pw * Pp + q];
    }
    float s = v[0] + v[1] + v[2];
    float s2 = v[0] * v[0] + v[1] * v[1] + v[2] * v[2];
    block_red2(s, s2, red);
    float mu = s * (1.f / PD);
    float var = s2 * (1.f / PD) - mu * mu;
    float r = rsqrtf(var + EPSf);
#pragma unroll
    for (int i = 0; i < 3; i++) {
        int d = t + i * 256;
        out[(long)pid * PD + d] = (half_t)((v[i] - mu) * r * g[d] + bb[d]);
    }
}

// ---------------- row LayerNorm (768 wide), templated output ----------------
template <typename T>
__global__ __launch_bounds__(256) void k_ln(
        const float* __restrict__ in, const float* __restrict__ g,
        const float* __restrict__ bb, T* __restrict__ out,
        long in_stride, long out_stride) {
    long row = blockIdx.x;
    const float* ip = in + row * in_stride;
    T* op = out + row * out_stride;
    int t = threadIdx.x;
    __shared__ float red[8];
    float v[3];
#pragma unroll
    for (int i = 0; i < 3; i++) v[i] = ip[t + i * 256];
    float s = v[0] + v[1] + v[2];
    float s2 = v[0] * v[0] + v[1] * v[1] + v[2] * v[2];
    block_red2(s, s2, red);
    float mu = s * (1.f / Dd);
    float var = s2 * (1.f / Dd) - mu * mu;
    float r = rsqrtf(var + EPSf);
#pragma unroll
    for (int i = 0; i < 3; i++) {
        int d = t + i * 256;
        op[d] = (T)((v[i] - mu) * r * g[d] + bb[d]);
    }
}

// ---------------- embed assemble: LN(tmp)+pos, cls+pos ----------------
__global__ __launch_bounds__(256) void k_embed(
        const float* __restrict__ tmp, const float* __restrict__ cls,
        const float* __restrict__ pos, const float* __restrict__ g,
        const float* __restrict__ bb, float* __restrict__ x) {
    int pid = blockIdx.x;
    int b = pid / Nn, n = pid % Nn;
    int t = threadIdx.x;
    float* xp = x + (long)pid * Dd;
    if (n == 0) {
#pragma unroll
        for (int i = 0; i < 3; i++) {
            int d = t + i * 256;
            xp[d] = cls[d] + pos[d];
        }
        return;
    }
    const float* ip = tmp + (long)(b * NPc + n - 1) * Dd;
    __shared__ float red[8];
    float v[3];
#pragma unroll
    for (int i = 0; i < 3; i++) v[i] = ip[t + i * 256];
    float s = v[0] + v[1] + v[2];
    float s2 = v[0] * v[0] + v[1] * v[1] + v[2] * v[2];
    block_red2(s, s2, red);
    float mu = s * (1.f / Dd);
    float var = s2 * (1.f / Dd) - mu * mu;
    float r = rsqrtf(var + EPSf);
#pragma unroll
    for (int i = 0; i < 3; i++) {
        int d = t + i * 256;
        xp[d] = (v[i] - mu) * r * g[d] + bb[d] + pos[(long)n * Dd + d];
    }
}

// ---------------- weight prep: fp32 W[K][N] -> f16 Wt[N][K] ----------------
__global__ __launch_bounds__(256) void k_wprep(
        const float* __restrict__ W, half_t* __restrict__ Wt, int K, int N) {
    W += (long)blockIdx.z * K * N;
    Wt += (long)blockIdx.z * K * N;
    __shared__ float tile[32][33];
    int n = blockIdx.x * 32 + threadIdx.x;
    int k0 = blockIdx.y * 32;
#pragma unroll
    for (int i = 0; i < 4; i++)
        tile[threadIdx.y + i * 8][threadIdx.x] = W[(long)(k0 + threadIdx.y + i * 8) * N + n];
    __syncthreads();
    int kk = k0 + threadIdx.x;
#pragma unroll
    for (int i = 0; i < 4; i++)
        Wt[(long)(blockIdx.x * 32 + threadIdx.y + i * 8) * K + kk] =
            (half_t)tile[threadIdx.x][threadIdx.y + i * 8];
}

// ---------------- head weight prep: fp32 [768][1000] -> f16 [1024][768] (pad 0) --------
__global__ __launch_bounds__(256) void k_wprep_head(
        const float* __restrict__ W, half_t* __restrict__ Wt) {
    __shared__ float tile[32][33];
    int n = blockIdx.x * 32 + threadIdx.x;
    int k0 = blockIdx.y * 32;
#pragma unroll
    for (int i = 0; i < 4; i++)
        tile[threadIdx.y + i * 8][threadIdx.x] =
            (n < NCLS) ? W[(long)(k0 + threadIdx.y + i * 8) * NCLS + n] : 0.f;
    __syncthreads();
    int kk = k0 + threadIdx.x;
#pragma unroll
    for (int i = 0; i < 4; i++)
        Wt[(long)(blockIdx.x * 32 + threadIdx.y + i * 8) * Dd + kk] =
            (half_t)tile[threadIdx.x][threadIdx.y + i * 8];
}

// ---------------- head GEMM: one thread per (row,col), f16 dot ----------------
__global__ __launch_bounds__(256) void k_head(
        const half_t* __restrict__ Ah, const half_t* __restrict__ Wh,
        const float* __restrict__ bias, float* __restrict__ out) {
    int idx = blockIdx.x * 256 + threadIdx.x;
    int row = idx >> 10, col = idx & 1023;
    if (col >= NCLS) return;
    const half_t* ap = Ah + (long)row * Dd;
    const half_t* wp = Wh + (long)col * Dd;
    float acc = 0.f;
#pragma unroll
    for (int k = 0; k < 96; k++) {
        half8 a = *(const half8*)&ap[k * 8];
        half8 w = *(const half8*)&wp[k * 8];
#pragma unroll
        for (int u = 0; u < 8; u++) acc += (float)a[u] * (float)w[u];
    }
    out[(long)row * NCLS + col] = acc + bias[col];
}

// ---------------- f16 MFMA GEMM ----------------
// OMODE=1 (qkv): C=q, C1=k head-major [b,h,n,64]; V third (n0>=1536) staged
//   TRANSPOSED in LDS then written lane-coalesced into Vt [b,h,64,224].
__device__ __forceinline__ half8 lds_frag(const uint32x4 (*L)[8], int row, int slot) {
    union { uint32x4 u; half8 h; } t;
    t.u = L[row][slot];
    return t.h;
}

template <int HASB, int HASR, typename CT, int OMODE>
__global__ __launch_bounds__(256, 2) void k_hgemm(
        const half_t* __restrict__ A, const half_t* __restrict__ Bt,
        const float* __restrict__ bias, const float* __restrict__ res,
        CT* __restrict__ C, CT* __restrict__ C1, half_t* __restrict__ Vt,
        int M, int N, int K) {
    __shared__ uint32x4 smem[2176];
    uint32x4 (*As)[8] = (uint32x4(*)[8])smem;
    uint32x4 (*Bs)[8] = (uint32x4(*)[8])(smem + 1024);
    const int tid = threadIdx.x;
    const int nwg = gridDim.x;
    const int q8 = nwg >> 3, r8 = nwg & 7;
    const int xc = blockIdx.x & 7, oo = blockIdx.x >> 3;
    const int tile = (xc < r8 ? xc * (q8 + 1) : r8 * (q8 + 1) + (xc - r8) * q8) + oo;
    const int gx = N >> 7;
    const int n0 = (tile % gx) * 128, m0 = (tile / gx) * 128;
    const int lane = tid & 63, w = tid >> 6;
    const int wrr = (w >> 1) * 64, wcc = (w & 1) * 64;
    const int lrow = lane & 15, lgrp = lane >> 4;

    int lm[4], sw[4];
    long gA[4], gB[4];
    const int cb = (tid & 7) * 8;
#pragma unroll
    for (int c = 0; c < 4; ++c) {
        lm[c] = c * 32 + (tid >> 3);
        sw[c] = (tid & 7) ^ (lm[c] & 7);
        int ma = m0 + lm[c];
        if (ma > M - 1) ma = M - 1;
        gA[c] = (long)ma * K + cb;
        gB[c] = (long)(n0 + lm[c]) * K + cb;
    }

    f32x4 acc[4][4] = {};
    uint32x4 ra[4], rb[4];
#pragma unroll
    for (int c = 0; c < 4; ++c) { ra[c] = *(const uint32x4*)(A + gA[c]); rb[c] = *(const uint32x4*)(Bt + gB[c]); }
#pragma unroll
    for (int c = 0; c < 4; ++c) { As[lm[c]][sw[c]] = ra[c]; Bs[lm[c]][sw[c]] = rb[c]; }
    __syncthreads();

    const int nst = K >> 6;
    for (int t = 0; t < nst; ++t) {
        if (t + 1 < nst) {
            const int k0 = (t + 1) << 6;
#pragma unroll
            for (int c = 0; c < 4; ++c) {
                ra[c] = *(const uint32x4*)(A + gA[c] + k0);
                rb[c] = *(const uint32x4*)(Bt + gB[c] + k0);
            }
        }
#pragma unroll
        for (int kh = 0; kh < 2; ++kh) {
            half8 af[4], bf[4];
#pragma unroll
            for (int i2 = 0; i2 < 4; ++i2) {
                int m = wrr + i2 * 16 + lrow;
                af[i2] = lds_frag(As, m, (kh * 4 + lgrp) ^ (m & 7));
                int n = wcc + i2 * 16 + lrow;
                bf[i2] = lds_frag(Bs, n, (kh * 4 + lgrp) ^ (n & 7));
            }
#pragma unroll
            for (int i2 = 0; i2 < 4; ++i2)
#pragma unroll
                for (int j2 = 0; j2 < 4; ++j2)
                    acc[i2][j2] = __builtin_amdgcn_mfma_f32_16x16x32_f16(af[i2], bf[j2], acc[i2][j2], 0, 0, 0);
        }
        if (t + 1 < nst) {
            __syncthreads();
#pragma unroll
            for (int c = 0; c < 4; ++c) { As[lm[c]][sw[c]] = ra[c]; Bs[lm[c]][sw[c]] = rb[c]; }
            __syncthreads();
        }
    }

    if constexpr (sizeof(CT) == 2) {
        if constexpr (OMODE == 1) {
            if (n0 >= 1536) {
                // V third: stage TRANSPOSED in LDS (Cs[col][token], stride 136),
                // then lane-coalesced scalar stores (consecutive lanes = consecutive nn).
                __syncthreads();
                half_t* Cs = (half_t*)smem;
#pragma unroll
                for (int i2 = 0; i2 < 4; ++i2)
#pragma unroll
                    for (int j2 = 0; j2 < 4; ++j2) {
                        int colc = wcc + j2 * 16 + lrow;
#pragma unroll
                        for (int q = 0; q < 4; ++q) {
                            int r = wrr + i2 * 16 + lgrp * 4 + q;
                            Cs[colc * 136 + r] = (half_t)acc[i2][j2][q];
                        }
                    }
                __syncthreads();
                const int rr = tid & 127;      // token offset (lane-consecutive)
                const int cbase = (tid >> 7) * 64;
                int token = m0 + rr;
                bool ok = token < M;
                int b = 0, nn = 0;
                if (ok) { b = token / Nn; nn = token - b * Nn; }
#pragma unroll
                for (int cc = 0; cc < 64; ++cc) {
                    int c = cbase + cc;
                    int rem = n0 + c - 1536;
                    int h = rem >> 6, d = rem & 63;
                    if (ok)
                        Vt[((long)(b * NH + h) * 64 + d) * 224 + nn] = Cs[c * 136 + rr];
                }
                return;
            }
        }
        __syncthreads();
        half_t* Cs = (half_t*)smem;
#pragma unroll
        for (int i2 = 0; i2 < 4; ++i2)
#pragma unroll
            for (int j2 = 0; j2 < 4; ++j2) {
                int colc = wcc + j2 * 16 + lrow;
                float bv = HASB ? bias[n0 + colc] : 0.f;
#pragma unroll
                for (int q = 0; q < 4; ++q) {
                    int r = wrr + i2 * 16 + lgrp * 4 + q;
                    Cs[r * 136 + colc] = (half_t)(acc[i2][j2][q] + bv);
                }
            }
        __syncthreads();
#pragma unroll
        for (int it = 0; it < 8; ++it) {
            int idx = tid + it * 256;
            int row = idx >> 4, cu = idx & 15;
            int token = m0 + row;
            if (token < M) {
                uint32x4 val = *(const uint32x4*)(Cs + row * 136 + cu * 8);
                if constexpr (OMODE == 1) {
                    int gc = n0 + cu * 8;
                    int which = gc >= 768 ? 1 : 0;
                    int rem = gc - which * 768;
                    int h = rem >> 6, d = rem & 63;
                    int b = token / Nn, nn = token - b * Nn;
                    CT* dst = (which == 0 ? C : C1);
                    __builtin_nontemporal_store(val,
                        (uint32x4*)(dst + (((long)(b * NH + h) * Nn + nn) << 6) + d));
                } else {
                    __builtin_nontemporal_store(val,
                        (uint32x4*)(C + (long)token * N + n0 + cu * 8));
                }
            }
        }
    } else {
#pragma unroll
        for (int i2 = 0; i2 < 4; ++i2)
#pragma unroll
            for (int j2 = 0; j2 < 4; ++j2) {
                int colc = n0 + wcc + j2 * 16 + lrow;
                float bv = HASB ? bias[colc] : 0.f;
#pragma unroll
                for (int q = 0; q < 4; ++q) {
                    int r = m0 + wrr + i2 * 16 + lgrp * 4 + q;
                    if (r < M) {
                        float v = acc[i2][j2][q] + bv;
                        if (HASR) v += res[(long)r * N + colc];
                        __builtin_nontemporal_store(v, &C[(long)r * N + colc]);
                    }
                }
            }
    }
}

// ---------------- attention stats: cross-head mu & rsqrt(var), fragment layout --------
__global__ __launch_bounds__(256) void k_stats(
        const half_t* __restrict__ qh, const half_t* __restrict__ kh,
        f32x4* __restrict__ muT, f32x4* __restrict__ rsT) {
    const int blk = (blockIdx.x & 7) * 169 + (blockIdx.x >> 3);   // 1352 = 8*169
    const int w = threadIdx.x >> 6, lane = threadIdx.x & 63;
    const int task = blk * 4 + w;                                  // 5408 = 32*169
    const int b = task / 169, r = task % 169;
    const int it = r / 13, jt = r % 13;
    const int lrow = lane & 15, lg = lane >> 4;
    const int i0 = it * 16, j0 = jt * 16;
    const int arow = min(i0 + lrow, Nn - 1);
    const int jr = min(j0 + lrow, Nn - 1);
    const int hbase = b * NH;

    float sv[4] = {}, sq[4] = {};
#pragma unroll
    for (int h = 0; h < NH; h++) {
        const half_t* Qp = qh + ((long)(hbase + h) * Nn) * 64;
        const half_t* Kp = kh + ((long)(hbase + h) * Nn) * 64;
        half8 af0 = *(const half8*)&Qp[(long)arow * 64 + lg * 8];
        half8 af1 = *(const half8*)&Qp[(long)arow * 64 + 32 + lg * 8];
        half8 bf0 = *(const half8*)&Kp[(long)jr * 64 + lg * 8];
        half8 bf1 = *(const half8*)&Kp[(long)jr * 64 + 32 + lg * 8];
        f32x4 acc = {};
        acc = __builtin_amdgcn_mfma_f32_16x16x32_f16(af0, bf0, acc, 0, 0, 0);
        acc = __builtin_amdgcn_mfma_f32_16x16x32_f16(af1, bf1, acc, 0, 0, 0);
#pragma unroll
        for (int q = 0; q < 4; q++) { sv[q] += acc[q]; sq[q] += acc[q] * acc[q]; }
    }
    f32x4 muv, rsv;
#pragma unroll
    for (int q = 0; q < 4; q++) {
        float mu = sv[q] * (1.f / NH);
        float var = (sq[q] - sv[q] * mu) * (1.f / (NH - 1));
        muv[q] = mu;
        rsv[q] = rsqrtf(var);
    }
    long idx = ((long)(b * 13 + it) * 13 + jt) * 64 + lane;
    muT[idx] = muv;
    rsT[idx] = rsv;
}

// ---------------- attention per head: S recompute + z-score + softmax + PV ----------------
__global__ __launch_bounds__(64) void k_attn2(
        const half_t* __restrict__ qh, const half_t* __restrict__ kh,
        const half_t* __restrict__ vt, const f32x4* __restrict__ muT,
        const f32x4* __restrict__ rsT, half_t* __restrict__ o) {
    __shared__ half_t PB[16][232];
    const int tile = (blockIdx.x & 7) * 624 + (blockIdx.x >> 3);  // 4992 = 8*624
    const int bh = tile / 13, it = tile % 13;
    const int b = bh / NH, h = bh % NH;
    const int i0 = it * 16;
    const int lane = threadIdx.x;
    const int lrow = lane & 15, lg = lane >> 4;
    const int arow = min(i0 + lrow, Nn - 1);

    for (int idx = lane; idx < 16 * 12; idx += 64) {
        int rr = idx / 12, u = idx % 12;
        *(unsigned int*)&PB[rr][208 + u * 2] = 0u;
    }

    const half_t* Qp = qh + ((long)bh * Nn) * 64;
    const half_t* Kp = kh + ((long)bh * Nn) * 64;
    half8 af0 = *(const half8*)&Qp[(long)arow * 64 + lg * 8];
    half8 af1 = *(const half8*)&Qp[(long)arow * 64 + 32 + lg * 8];
    const f32x4* muB = muT + ((long)(b * 13 + it) * 13) * 64 + lane;
    const f32x4* rsB = rsT + ((long)(b * 13 + it) * 13) * 64 + lane;

    float ez[13][4];
    float mx[4] = {-1e30f, -1e30f, -1e30f, -1e30f};
#pragma unroll
    for (int jt = 0; jt < 13; jt++) {
        int jr = min(jt * 16 + lrow, Nn - 1);
        half8 bf0 = *(const half8*)&Kp[(long)jr * 64 + lg * 8];
        half8 bf1 = *(const half8*)&Kp[(long)jr * 64 + 32 + lg * 8];
        f32x4 acc = {};
        acc = __builtin_amdgcn_mfma_f32_16x16x32_f16(af0, bf0, acc, 0, 0, 0);
        acc = __builtin_amdgcn_mfma_f32_16x16x32_f16(af1, bf1, acc, 0, 0, 0);
        f32x4 mu4 = muB[jt * 64];
        f32x4 rs4 = rsB[jt * 64];
        bool joob = (jt * 16 + lrow) > Nn - 1;
#pragma unroll
        for (int q = 0; q < 4; q++) {
            float z = (acc[q] - mu4[q]) * rs4[q];
            if (joob) z = -1e30f;
            ez[jt][q] = z;
            mx[q] = fmaxf(mx[q], z);
        }
    }
#pragma unroll
    for (int st = 1; st <= 8; st <<= 1)
#pragma unroll
        for (int q = 0; q < 4; q++) mx[q] = fmaxf(mx[q], __shfl_xor(mx[q], st));
    float sm[4] = {0.f, 0.f, 0.f, 0.f};
#pragma unroll
    for (int jt = 0; jt < 13; jt++)
#pragma unroll
        for (int q = 0; q < 4; q++) {
            float e = __expf(ez[jt][q] - mx[q]);
            ez[jt][q] = e;
            sm[q] += e;
        }
#pragma unroll
    for (int st = 1; st <= 8; st <<= 1)
#pragma unroll
        for (int q = 0; q < 4; q++) sm[q] += __shfl_xor(sm[q], st);
    float inv[4];
#pragma unroll
    for (int q = 0; q < 4; q++) inv[q] = 1.f / sm[q];
#pragma unroll
    for (int jt = 0; jt < 13; jt++)
#pragma unroll
        for (int q = 0; q < 4; q++)
            PB[lg * 4 + q][jt * 16 + lrow] = (half_t)(ez[jt][q] * inv[q]);
    __syncthreads();

    const half_t* Vtp = vt + ((long)bh * 64) * 224;
#pragma unroll
    for (int dt = 0; dt < 4; dt++) {
        f32x4 oacc = {};
#pragma unroll
        for (int kt = 0; kt < 7; kt++) {
            half8 pa = *(const half8*)&PB[lrow][kt * 32 + lg * 8];
            half8 vb = *(const half8*)&Vtp[(long)(dt * 16 + lrow) * 224 + kt * 32 + lg * 8];
            oacc = __builtin_amdgcn_mfma_f32_16x16x32_f16(pa, vb, oacc, 0, 0, 0);
        }
#pragma unroll
        for (int q = 0; q < 4; q++) {
            int i = i0 + lg * 4 + q;
            if (i < Nn)
                o[((long)(b * Nn) + i) * INNERc + h * 64 + dt * 16 + lrow] = (half_t)oacc[q];
        }
    }
}

// ---------------- host launcher ----------------
extern "C" void kernel_launch(void* const* d_in, const int* in_sizes, int n_in,
                              void* d_out, int out_size, void* d_ws, size_t ws_size,
                              hipStream_t stream) {
    const float* img     = (const float*)d_in[0];
    const float* patch_g = (const float*)d_in[2];
    const float* patch_b = (const float*)d_in[3];
    const float* W_patch = (const float*)d_in[4];
    const float* b_patch = (const float*)d_in[5];
    const float* emb_g   = (const float*)d_in[6];
    const float* emb_b   = (const float*)d_in[7];
    const float* pos     = (const float*)d_in[8];
    const float* cls     = (const float*)d_in[9];
    const float* ln_g    = (const float*)d_in[10];
    const float* ln_b    = (const float*)d_in[11];
    const float* W_qkv   = (const float*)d_in[12];
    const float* W_out   = (const float*)d_in[13];
    const float* b_out   = (const float*)d_in[14];
    const float* fin_g   = (const float*)d_in[15];
    const float* fin_b   = (const float*)d_in[16];
    const float* W_head  = (const float*)d_in[17];
    const float* b_head  = (const float*)d_in[18];
    float* out = (float*)d_out;

    const long SZ_XD  = (long)Bc * Nn * Dd;            // 4,841,472
    const long SZ_HD  = (long)Bc * NH * Nn * DHd;      // 4,841,472
    const long SZ_VT  = (long)Bc * NH * 64 * 224;      // 5,505,024
    const long SZ_TMP = (long)Bc * NPc * Dd;
    const long SZ_MU  = (long)Bc * 169 * 256 + 1024;   // fragment-layout stats

    float* x    = (float*)d_ws;
    float* tmp  = x + SZ_XD;
    float* muG  = tmp + SZ_TMP;
    float* rsG  = muG + SZ_MU;
    half_t* xh       = (half_t*)(rsG + SZ_MU);
    half_t* qhb      = xh + SZ_XD;
    half_t* khb      = qhb + SZ_HD;
    half_t* vtb      = khb + SZ_HD;
    half_t* clsh     = vtb + SZ_VT;                         // 32x768 f16
    half_t* wh_head  = clsh + 32 * Dd;                      // 1024x768 f16
    half_t* wt_patch = wh_head + 1024 * Dd;
    half_t* wt_qkv   = wt_patch + (long)Dd * Dd;
    half_t* wt_out   = wt_qkv + (long)DEPTHc * 3 * INNERc * Dd;

    // ---- weight prep ----
    hipLaunchKernelGGL(k_wprep, dim3(Dd / 32, Dd / 32, 1), dim3(32, 8), 0, stream,
                       W_patch, wt_patch, Dd, Dd);
    hipLaunchKernelGGL(k_wprep, dim3(3 * INNERc / 32, Dd / 32, DEPTHc), dim3(32, 8), 0, stream,
                       W_qkv, wt_qkv, Dd, 3 * INNERc);
    hipLaunchKernelGGL(k_wprep, dim3(Dd / 32, Dd / 32, DEPTHc), dim3(32, 8), 0, stream,
                       W_out, wt_out, Dd, Dd);
    hipLaunchKernelGGL(k_wprep_head, dim3(32, 24), dim3(32, 8), 0, stream,
                       W_head, wh_head);

    // 1. patchify + patch LN -> xh (f16)
    hipLaunchKernelGGL(k_patch_ln, dim3(Bc * NPc), dim3(256), 0, stream,
                       img, patch_g, patch_b, xh);
    // 2. patch GEMM (+b_patch) -> tmp fp32
    hipLaunchKernelGGL((k_hgemm<1, 0, float, 0>), dim3(6 * 49), dim3(256), 0, stream,
                       xh, wt_patch, b_patch, nullptr,
                       tmp, nullptr, nullptr, Bc * NPc, Dd, Dd);
    // 3. emb LN + cls concat + pos add -> x
    hipLaunchKernelGGL(k_embed, dim3(Bc * Nn), dim3(256), 0, stream,
                       tmp, cls, pos, emb_g, emb_b, x);

    const int Mrows = Bc * Nn;  // 6304
    for (int l = 0; l < DEPTHc; l++) {
        const float* g  = ln_g + (long)l * Dd;
        const float* bb = ln_b + (long)l * Dd;
        const half_t* Wq = wt_qkv + (long)l * 3 * INNERc * Dd;
        const half_t* Wo = wt_out + (long)l * Dd * Dd;
        const float* bo = b_out + (long)l * Dd;
        hipLaunchKernelGGL((k_ln<half_t>), dim3(Mrows), dim3(256), 0, stream,
                           x, g, bb, xh, (long)Dd, (long)Dd);
        // qkv GEMM; q/k head-major, V staged in LDS + written transposed coalesced
        hipLaunchKernelGGL((k_hgemm<0, 0, half_t, 1>), dim3(18 * 50), dim3(256), 0, stream,
                           xh, Wq, nullptr, nullptr,
                           qhb, khb, vtb, Mrows, 3 * INNERc, Dd);
        hipLaunchKernelGGL(k_stats, dim3(1352), dim3(256), 0, stream,
                           qhb, khb, (f32x4*)muG, (f32x4*)rsG);
        hipLaunchKernelGGL(k_attn2, dim3(4992), dim3(64), 0, stream,
                           qhb, khb, vtb, (const f32x4*)muG, (const f32x4*)rsG, xh);
        hipLaunchKernelGGL((k_hgemm<1, 1, float, 0>), dim3(6 * 50), dim3(256), 0, stream,
                           xh, Wo, bo, x,
                           x, nullptr, nullptr, Mrows, Dd, Dd);
    }
    // final LN (cls rows only) -> clsh f16
    hipLaunchKernelGGL((k_ln<half_t>), dim3(Bc), dim3(256), 0, stream,
                       x, fin_g, fin_b, clsh, (long)Nn * Dd, (long)Dd);
    // head GEMM: f16 dot per (row,col)
    hipLaunchKernelGGL(k_head, dim3(128), dim3(256), 0, stream,
                       clsh, wh_head, b_head, out);
}

// Round 14
// 1702.271 us; speedup vs baseline: 2.1535x; 1.0385x over previous
//
#include <hip/hip_runtime.h>
#include <math.h>

// ---------------- problem constants ----------------
constexpr int Bc = 32, Cch = 3, Hh = 224, Ww = 224, Pp = 16;
constexpr int Dd = 768, NH = 12, DHd = 64, INNERc = 768;
constexpr int DEPTHc = 12, NCLS = 1000;
constexpr int NPc = 196, Nn = 197, PD = 768;
constexpr float EPSf = 1e-5f;

typedef _Float16 half_t;
typedef __attribute__((ext_vector_type(8))) _Float16 half8;
typedef __attribute__((ext_vector_type(4))) float f32x4;
typedef __attribute__((ext_vector_type(4))) unsigned int uint32x4;

// ---------------- reduction helpers ----------------
__device__ __forceinline__ float wave_red_sum(float v) {
#pragma unroll
    for (int m = 32; m; m >>= 1) v += __shfl_xor(v, m);
    return v;
}

__device__ __forceinline__ void block_red2(float& s, float& s2, float* red) {
    s = wave_red_sum(s);
    s2 = wave_red_sum(s2);
    int wid = threadIdx.x >> 6, lane = threadIdx.x & 63;
    if (lane == 0) { red[wid] = s; red[4 + wid] = s2; }
    __syncthreads();
    s = red[0] + red[1] + red[2] + red[3];
    s2 = red[4] + red[5] + red[6] + red[7];
}

// ---------------- patchify + patch LN -> f16 ----------------
__global__ __launch_bounds__(256) void k_patch_ln(
        const float* __restrict__ img, const float* __restrict__ g,
        const float* __restrict__ bb, half_t* __restrict__ out) {
    int pid = blockIdx.x;
    int b = pid / NPc, n = pid % NPc;
    int ph = n / 14, pw = n % 14;
    int t = threadIdx.x;
    __shared__ float red[8];
    float v[3];
#pragma unroll
    for (int i = 0; i < 3; i++) {
        int d = t + i * 256;
        int c = d % 3, q = (d / 3) & 15, p = d / 48;
        v[i] = img[((long)(b * Cch + c) * Hh + ph * Pp + p) * Ww + pw * Pp + q];
    }
    float s = v[0] + v[1] + v[2];
    float s2 = v[0] * v[0] + v[1] * v[1] + v[2] * v[2];
    block_red2(s, s2, red);
    float mu = s * (1.f / PD);
    float var = s2 * (1.f / PD) - mu * mu;
    float r = rsqrtf(var + EPSf);
#pragma unroll
    for (int i = 0; i < 3; i++) {
        int d = t + i * 256;
        out[(long)pid * PD + d] = (half_t)((v[i] - mu) * r * g[d] + bb[d]);
    }
}

// ---------------- row LayerNorm (768 wide), templated output ----------------
template <typename T>
__global__ __launch_bounds__(256) void k_ln(
        const float* __restrict__ in, const float* __restrict__ g,
        const float* __restrict__ bb, T* __restrict__ out,
        long in_stride, long out_stride) {
    long row = blockIdx.x;
    const float* ip = in + row * in_stride;
    T* op = out + row * out_stride;
    int t = threadIdx.x;
    __shared__ float red[8];
    float v[3];
#pragma unroll
    for (int i = 0; i < 3; i++) v[i] = ip[t + i * 256];
    float s = v[0] + v[1] + v[2];
    float s2 = v[0] * v[0] + v[1] * v[1] + v[2] * v[2];
    block_red2(s, s2, red);
    float mu = s * (1.f / Dd);
    float var = s2 * (1.f / Dd) - mu * mu;
    float r = rsqrtf(var + EPSf);
#pragma unroll
    for (int i = 0; i < 3; i++) {
        int d = t + i * 256;
        op[d] = (T)((v[i] - mu) * r * g[d] + bb[d]);
    }
}

// ---------------- embed assemble: LN(tmp)+pos, cls+pos ----------------
__global__ __launch_bounds__(256) void k_embed(
        const float* __restrict__ tmp, const float* __restrict__ cls,
        const float* __restrict__ pos, const float* __restrict__ g,
        const float* __restrict__ bb, float* __restrict__ x) {
    int pid = blockIdx.x;
    int b = pid / Nn, n = pid % Nn;
    int t = threadIdx.x;
    float* xp = x + (long)pid * Dd;
    if (n == 0) {
#pragma unroll
        for (int i = 0; i < 3; i++) {
            int d = t + i * 256;
            xp[d] = cls[d] + pos[d];
        }
        return;
    }
    const float* ip = tmp + (long)(b * NPc + n - 1) * Dd;
    __shared__ float red[8];
    float v[3];
#pragma unroll
    for (int i = 0; i < 3; i++) v[i] = ip[t + i * 256];
    float s = v[0] + v[1] + v[2];
    float s2 = v[0] * v[0] + v[1] * v[1] + v[2] * v[2];
    block_red2(s, s2, red);
    float mu = s * (1.f / Dd);
    float var = s2 * (1.f / Dd) - mu * mu;
    float r = rsqrtf(var + EPSf);
#pragma unroll
    for (int i = 0; i < 3; i++) {
        int d = t + i * 256;
        xp[d] = (v[i] - mu) * r * g[d] + bb[d] + pos[(long)n * Dd + d];
    }
}

// ---------------- weight prep: fp32 W[K][N] -> f16 Wt[N][K] ----------------
__global__ __launch_bounds__(256) void k_wprep(
        const float* __restrict__ W, half_t* __restrict__ Wt, int K, int N) {
    W += (long)blockIdx.z * K * N;
    Wt += (long)blockIdx.z * K * N;
    __shared__ float tile[32][33];
    int n = blockIdx.x * 32 + threadIdx.x;
    int k0 = blockIdx.y * 32;
#pragma unroll
    for (int i = 0; i < 4; i++)
        tile[threadIdx.y + i * 8][threadIdx.x] = W[(long)(k0 + threadIdx.y + i * 8) * N + n];
    __syncthreads();
    int kk = k0 + threadIdx.x;
#pragma unroll
    for (int i = 0; i < 4; i++)
        Wt[(long)(blockIdx.x * 32 + threadIdx.y + i * 8) * K + kk] =
            (half_t)tile[threadIdx.x][threadIdx.y + i * 8];
}

// ---------------- head weight prep: fp32 [768][1000] -> f16 [1024][768] (pad 0) --------
__global__ __launch_bounds__(256) void k_wprep_head(
        const float* __restrict__ W, half_t* __restrict__ Wt) {
    __shared__ float tile[32][33];
    int n = blockIdx.x * 32 + threadIdx.x;
    int k0 = blockIdx.y * 32;
#pragma unroll
    for (int i = 0; i < 4; i++)
        tile[threadIdx.y + i * 8][threadIdx.x] =
            (n < NCLS) ? W[(long)(k0 + threadIdx.y + i * 8) * NCLS + n] : 0.f;
    __syncthreads();
    int kk = k0 + threadIdx.x;
#pragma unroll
    for (int i = 0; i < 4; i++)
        Wt[(long)(blockIdx.x * 32 + threadIdx.y + i * 8) * Dd + kk] =
            (half_t)tile[threadIdx.x][threadIdx.y + i * 8];
}

// ---------------- head GEMM: one thread per (row,col), f16 dot ----------------
__global__ __launch_bounds__(256) void k_head(
        const half_t* __restrict__ Ah, const half_t* __restrict__ Wh,
        const float* __restrict__ bias, float* __restrict__ out) {
    int idx = blockIdx.x * 256 + threadIdx.x;
    int row = idx >> 10, col = idx & 1023;
    if (col >= NCLS) return;
    const half_t* ap = Ah + (long)row * Dd;
    const half_t* wp = Wh + (long)col * Dd;
    float acc = 0.f;
#pragma unroll
    for (int k = 0; k < 96; k++) {
        half8 a = *(const half8*)&ap[k * 8];
        half8 w = *(const half8*)&wp[k * 8];
#pragma unroll
        for (int u = 0; u < 8; u++) acc += (float)a[u] * (float)w[u];
    }
    out[(long)row * NCLS + col] = acc + bias[col];
}

// ---------------- f16 MFMA GEMM ----------------
// Staging via global_load_lds width=16 (m97 structure): LDS dest linear
// (wave-uniform base + lane*16); global SOURCE pre-swizzled by chunk^(row&7)
// so the existing XOR-swizzled ds_read fragment path is unchanged (m173).
// OMODE=1 (qkv): C=q, C1=k head-major [b,h,n,64]; V third (n0>=1536) staged
//   TRANSPOSED in LDS then written lane-coalesced into Vt [b,h,64,224].
__device__ __forceinline__ half8 lds_frag(const uint32x4 (*L)[8], int row, int slot) {
    union { uint32x4 u; half8 h; } t;
    t.u = L[row][slot];
    return t.h;
}

__device__ __forceinline__ void gload16(const half_t* g, uint32x4* l) {
    __builtin_amdgcn_global_load_lds(
        (const __attribute__((address_space(1))) unsigned int*)g,
        (__attribute__((address_space(3))) unsigned int*)l,
        16, 0, 0);
}

template <int HASB, int HASR, typename CT, int OMODE>
__global__ __launch_bounds__(256, 2) void k_hgemm(
        const half_t* __restrict__ A, const half_t* __restrict__ Bt,
        const float* __restrict__ bias, const float* __restrict__ res,
        CT* __restrict__ C, CT* __restrict__ C1, half_t* __restrict__ Vt,
        int M, int N, int K) {
    __shared__ uint32x4 smem[2176];   // A[1024] | B[1024]; epilogue aliases half Cs
    uint32x4 (*As)[8] = (uint32x4(*)[8])smem;
    uint32x4 (*Bs)[8] = (uint32x4(*)[8])(smem + 1024);
    const int tid = threadIdx.x;
    const int nwg = gridDim.x;
    const int q8 = nwg >> 3, r8 = nwg & 7;
    const int xc = blockIdx.x & 7, oo = blockIdx.x >> 3;
    const int tile = (xc < r8 ? xc * (q8 + 1) : r8 * (q8 + 1) + (xc - r8) * q8) + oo;
    const int gx = N >> 7;
    const int n0 = (tile % gx) * 128, m0 = (tile / gx) * 128;
    const int lane = tid & 63, w = tid >> 6;
    const int wrr = (w >> 1) * 64, wcc = (w & 1) * 64;
    const int lrow = lane & 15, lgrp = lane >> 4;

    // staging: each wave owns 32 rows (4 calls x 8 rows); lane l covers
    // row (l>>3), slot (l&7) of the 1KB span. Source chunk pre-swizzled.
    int ldsOff[4];
    long gsA[4], gsB[4];
#pragma unroll
    for (int c = 0; c < 4; ++c) {
        int r = w * 32 + c * 8 + (lane >> 3);
        int chunk = (lane & 7) ^ (r & 7);
        ldsOff[c] = (w * 32 + c * 8) * 8;
        gsA[c] = (long)min(m0 + r, M - 1) * K + chunk * 8;
        gsB[c] = (long)(n0 + r) * K + chunk * 8;
    }

    f32x4 acc[4][4] = {};

#define STAGE(k0)                                         \
    {                                                     \
        _Pragma("unroll")                                 \
        for (int c = 0; c < 4; ++c) {                     \
            gload16(A + gsA[c] + (k0), smem + ldsOff[c]); \
            gload16(Bt + gsB[c] + (k0), smem + 1024 + ldsOff[c]); \
        }                                                 \
    }

    STAGE(0);
    __syncthreads();

    const int nst = K >> 6;
    for (int t = 0; t < nst; ++t) {
#pragma unroll
        for (int kh = 0; kh < 2; ++kh) {
            half8 af[4], bf[4];
#pragma unroll
            for (int i2 = 0; i2 < 4; ++i2) {
                int m = wrr + i2 * 16 + lrow;
                af[i2] = lds_frag(As, m, (kh * 4 + lgrp) ^ (m & 7));
                int n = wcc + i2 * 16 + lrow;
                bf[i2] = lds_frag(Bs, n, (kh * 4 + lgrp) ^ (n & 7));
            }
#pragma unroll
            for (int i2 = 0; i2 < 4; ++i2)
#pragma unroll
                for (int j2 = 0; j2 < 4; ++j2)
                    acc[i2][j2] = __builtin_amdgcn_mfma_f32_16x16x32_f16(af[i2], bf[j2], acc[i2][j2], 0, 0, 0);
        }
        if (t + 1 < nst) {
            __syncthreads();            // all reads of current tile done
            STAGE((t + 1) << 6);        // async global->LDS
            __syncthreads();            // loads complete (vmcnt drained)
        }
    }
#undef STAGE

    if constexpr (sizeof(CT) == 2) {
        if constexpr (OMODE == 1) {
            if (n0 >= 1536) {
                // V third: stage TRANSPOSED in LDS (Cs[col][token], stride 136),
                // then lane-coalesced scalar stores (consecutive lanes = consecutive nn).
                __syncthreads();
                half_t* Cs = (half_t*)smem;
#pragma unroll
                for (int i2 = 0; i2 < 4; ++i2)
#pragma unroll
                    for (int j2 = 0; j2 < 4; ++j2) {
                        int colc = wcc + j2 * 16 + lrow;
#pragma unroll
                        for (int q = 0; q < 4; ++q) {
                            int r = wrr + i2 * 16 + lgrp * 4 + q;
                            Cs[colc * 136 + r] = (half_t)acc[i2][j2][q];
                        }
                    }
                __syncthreads();
                const int rr = tid & 127;      // token offset (lane-consecutive)
                const int cbase = (tid >> 7) * 64;
                int token = m0 + rr;
                bool ok = token < M;
                int b = 0, nn = 0;
                if (ok) { b = token / Nn; nn = token - b * Nn; }
#pragma unroll
                for (int cc = 0; cc < 64; ++cc) {
                    int c = cbase + cc;
                    int rem = n0 + c - 1536;
                    int h = rem >> 6, d = rem & 63;
                    if (ok)
                        Vt[((long)(b * NH + h) * 64 + d) * 224 + nn] = Cs[c * 136 + rr];
                }
                return;
            }
        }
        __syncthreads();
        half_t* Cs = (half_t*)smem;
#pragma unroll
        for (int i2 = 0; i2 < 4; ++i2)
#pragma unroll
            for (int j2 = 0; j2 < 4; ++j2) {
                int colc = wcc + j2 * 16 + lrow;
                float bv = HASB ? bias[n0 + colc] : 0.f;
#pragma unroll
                for (int q = 0; q < 4; ++q) {
                    int r = wrr + i2 * 16 + lgrp * 4 + q;
                    Cs[r * 136 + colc] = (half_t)(acc[i2][j2][q] + bv);
                }
            }
        __syncthreads();
#pragma unroll
        for (int it = 0; it < 8; ++it) {
            int idx = tid + it * 256;
            int row = idx >> 4, cu = idx & 15;
            int token = m0 + row;
            if (token < M) {
                uint32x4 val = *(const uint32x4*)(Cs + row * 136 + cu * 8);
                if constexpr (OMODE == 1) {
                    int gc = n0 + cu * 8;
                    int which = gc >= 768 ? 1 : 0;
                    int rem = gc - which * 768;
                    int h = rem >> 6, d = rem & 63;
                    int b = token / Nn, nn = token - b * Nn;
                    CT* dst = (which == 0 ? C : C1);
                    __builtin_nontemporal_store(val,
                        (uint32x4*)(dst + (((long)(b * NH + h) * Nn + nn) << 6) + d));
                } else {
                    __builtin_nontemporal_store(val,
                        (uint32x4*)(C + (long)token * N + n0 + cu * 8));
                }
            }
        }
    } else {
#pragma unroll
        for (int i2 = 0; i2 < 4; ++i2)
#pragma unroll
            for (int j2 = 0; j2 < 4; ++j2) {
                int colc = n0 + wcc + j2 * 16 + lrow;
                float bv = HASB ? bias[colc] : 0.f;
#pragma unroll
                for (int q = 0; q < 4; ++q) {
                    int r = m0 + wrr + i2 * 16 + lgrp * 4 + q;
                    if (r < M) {
                        float v = acc[i2][j2][q] + bv;
                        if (HASR) v += res[(long)r * N + colc];
                        __builtin_nontemporal_store(v, &C[(long)r * N + colc]);
                    }
                }
            }
    }
}

// ---------------- attention stats: cross-head mu & rsqrt(var), fragment layout --------
__global__ __launch_bounds__(256) void k_stats(
        const half_t* __restrict__ qh, const half_t* __restrict__ kh,
        f32x4* __restrict__ muT, f32x4* __restrict__ rsT) {
    const int blk = (blockIdx.x & 7) * 169 + (blockIdx.x >> 3);   // 1352 = 8*169
    const int w = threadIdx.x >> 6, lane = threadIdx.x & 63;
    const int task = blk * 4 + w;                                  // 5408 = 32*169
    const int b = task / 169, r = task % 169;
    const int it = r / 13, jt = r % 13;
    const int lrow = lane & 15, lg = lane >> 4;
    const int i0 = it * 16, j0 = jt * 16;
    const int arow = min(i0 + lrow, Nn - 1);
    const int jr = min(j0 + lrow, Nn - 1);
    const int hbase = b * NH;

    float sv[4] = {}, sq[4] = {};
#pragma unroll
    for (int h = 0; h < NH; h++) {
        const half_t* Qp = qh + ((long)(hbase + h) * Nn) * 64;
        const half_t* Kp = kh + ((long)(hbase + h) * Nn) * 64;
        half8 af0 = *(const half8*)&Qp[(long)arow * 64 + lg * 8];
        half8 af1 = *(const half8*)&Qp[(long)arow * 64 + 32 + lg * 8];
        half8 bf0 = *(const half8*)&Kp[(long)jr * 64 + lg * 8];
        half8 bf1 = *(const half8*)&Kp[(long)jr * 64 + 32 + lg * 8];
        f32x4 acc = {};
        acc = __builtin_amdgcn_mfma_f32_16x16x32_f16(af0, bf0, acc, 0, 0, 0);
        acc = __builtin_amdgcn_mfma_f32_16x16x32_f16(af1, bf1, acc, 0, 0, 0);
#pragma unroll
        for (int q = 0; q < 4; q++) { sv[q] += acc[q]; sq[q] += acc[q] * acc[q]; }
    }
    f32x4 muv, rsv;
#pragma unroll
    for (int q = 0; q < 4; q++) {
        float mu = sv[q] * (1.f / NH);
        float var = (sq[q] - sv[q] * mu) * (1.f / (NH - 1));
        muv[q] = mu;
        rsv[q] = rsqrtf(var);
    }
    long idx = ((long)(b * 13 + it) * 13 + jt) * 64 + lane;
    muT[idx] = muv;
    rsT[idx] = rsv;
}

// ---------------- attention per head: S recompute + z-score + softmax + PV ----------------
__global__ __launch_bounds__(64) void k_attn2(
        const half_t* __restrict__ qh, const half_t* __restrict__ kh,
        const half_t* __restrict__ vt, const f32x4* __restrict__ muT,
        const f32x4* __restrict__ rsT, half_t* __restrict__ o) {
    __shared__ half_t PB[16][232];
    const int tile = (blockIdx.x & 7) * 624 + (blockIdx.x >> 3);  // 4992 = 8*624
    const int bh = tile / 13, it = tile % 13;
    const int b = bh / NH, h = bh % NH;
    const int i0 = it * 16;
    const int lane = threadIdx.x;
    const int lrow = lane & 15, lg = lane >> 4;
    const int arow = min(i0 + lrow, Nn - 1);

    for (int idx = lane; idx < 16 * 12; idx += 64) {
        int rr = idx / 12, u = idx % 12;
        *(unsigned int*)&PB[rr][208 + u * 2] = 0u;
    }

    const half_t* Qp = qh + ((long)bh * Nn) * 64;
    const half_t* Kp = kh + ((long)bh * Nn) * 64;
    half8 af0 = *(const half8*)&Qp[(long)arow * 64 + lg * 8];
    half8 af1 = *(const half8*)&Qp[(long)arow * 64 + 32 + lg * 8];
    const f32x4* muB = muT + ((long)(b * 13 + it) * 13) * 64 + lane;
    const f32x4* rsB = rsT + ((long)(b * 13 + it) * 13) * 64 + lane;

    float ez[13][4];
    float mx[4] = {-1e30f, -1e30f, -1e30f, -1e30f};
#pragma unroll
    for (int jt = 0; jt < 13; jt++) {
        int jr = min(jt * 16 + lrow, Nn - 1);
        half8 bf0 = *(const half8*)&Kp[(long)jr * 64 + lg * 8];
        half8 bf1 = *(const half8*)&Kp[(long)jr * 64 + 32 + lg * 8];
        f32x4 acc = {};
        acc = __builtin_amdgcn_mfma_f32_16x16x32_f16(af0, bf0, acc, 0, 0, 0);
        acc = __builtin_amdgcn_mfma_f32_16x16x32_f16(af1, bf1, acc, 0, 0, 0);
        f32x4 mu4 = muB[jt * 64];
        f32x4 rs4 = rsB[jt * 64];
        bool joob = (jt * 16 + lrow) > Nn - 1;
#pragma unroll
        for (int q = 0; q < 4; q++) {
            float z = (acc[q] - mu4[q]) * rs4[q];
            if (joob) z = -1e30f;
            ez[jt][q] = z;
            mx[q] = fmaxf(mx[q], z);
        }
    }
#pragma unroll
    for (int st = 1; st <= 8; st <<= 1)
#pragma unroll
        for (int q = 0; q < 4; q++) mx[q] = fmaxf(mx[q], __shfl_xor(mx[q], st));
    float sm[4] = {0.f, 0.f, 0.f, 0.f};
#pragma unroll
    for (int jt = 0; jt < 13; jt++)
#pragma unroll
        for (int q = 0; q < 4; q++) {
            float e = __expf(ez[jt][q] - mx[q]);
            ez[jt][q] = e;
            sm[q] += e;
        }
#pragma unroll
    for (int st = 1; st <= 8; st <<= 1)
#pragma unroll
        for (int q = 0; q < 4; q++) sm[q] += __shfl_xor(sm[q], st);
    float inv[4];
#pragma unroll
    for (int q = 0; q < 4; q++) inv[q] = 1.f / sm[q];
#pragma unroll
    for (int jt = 0; jt < 13; jt++)
#pragma unroll
        for (int q = 0; q < 4; q++)
            PB[lg * 4 + q][jt * 16 + lrow] = (half_t)(ez[jt][q] * inv[q]);
    __syncthreads();

    const half_t* Vtp = vt + ((long)bh * 64) * 224;
#pragma unroll
    for (int dt = 0; dt < 4; dt++) {
        f32x4 oacc = {};
#pragma unroll
        for (int kt = 0; kt < 7; kt++) {
            half8 pa = *(const half8*)&PB[lrow][kt * 32 + lg * 8];
            half8 vb = *(const half8*)&Vtp[(long)(dt * 16 + lrow) * 224 + kt * 32 + lg * 8];
            oacc = __builtin_amdgcn_mfma_f32_16x16x32_f16(pa, vb, oacc, 0, 0, 0);
        }
#pragma unroll
        for (int q = 0; q < 4; q++) {
            int i = i0 + lg * 4 + q;
            if (i < Nn)
                o[((long)(b * Nn) + i) * INNERc + h * 64 + dt * 16 + lrow] = (half_t)oacc[q];
        }
    }
}

// ---------------- host launcher ----------------
extern "C" void kernel_launch(void* const* d_in, const int* in_sizes, int n_in,
                              void* d_out, int out_size, void* d_ws, size_t ws_size,
                              hipStream_t stream) {
    const float* img     = (const float*)d_in[0];
    const float* patch_g = (const float*)d_in[2];
    const float* patch_b = (const float*)d_in[3];
    const float* W_patch = (const float*)d_in[4];
    const float* b_patch = (const float*)d_in[5];
    const float* emb_g   = (const float*)d_in[6];
    const float* emb_b   = (const float*)d_in[7];
    const float* pos     = (const float*)d_in[8];
    const float* cls     = (const float*)d_in[9];
    const float* ln_g    = (const float*)d_in[10];
    const float* ln_b    = (const float*)d_in[11];
    const float* W_qkv   = (const float*)d_in[12];
    const float* W_out   = (const float*)d_in[13];
    const float* b_out   = (const float*)d_in[14];
    const float* fin_g   = (const float*)d_in[15];
    const float* fin_b   = (const float*)d_in[16];
    const float* W_head  = (const float*)d_in[17];
    const float* b_head  = (const float*)d_in[18];
    float* out = (float*)d_out;

    const long SZ_XD  = (long)Bc * Nn * Dd;            // 4,841,472
    const long SZ_HD  = (long)Bc * NH * Nn * DHd;      // 4,841,472
    const long SZ_VT  = (long)Bc * NH * 64 * 224;      // 5,505,024
    const long SZ_TMP = (long)Bc * NPc * Dd;
    const long SZ_MU  = (long)Bc * 169 * 256 + 1024;   // fragment-layout stats

    float* x    = (float*)d_ws;
    float* tmp  = x + SZ_XD;
    float* muG  = tmp + SZ_TMP;
    float* rsG  = muG + SZ_MU;
    half_t* xh       = (half_t*)(rsG + SZ_MU);
    half_t* qhb      = xh + SZ_XD;
    half_t* khb      = qhb + SZ_HD;
    half_t* vtb      = khb + SZ_HD;
    half_t* clsh     = vtb + SZ_VT;                         // 32x768 f16
    half_t* wh_head  = clsh + 32 * Dd;                      // 1024x768 f16
    half_t* wt_patch = wh_head + 1024 * Dd;
    half_t* wt_qkv   = wt_patch + (long)Dd * Dd;
    half_t* wt_out   = wt_qkv + (long)DEPTHc * 3 * INNERc * Dd;

    // ---- weight prep ----
    hipLaunchKernelGGL(k_wprep, dim3(Dd / 32, Dd / 32, 1), dim3(32, 8), 0, stream,
                       W_patch, wt_patch, Dd, Dd);
    hipLaunchKernelGGL(k_wprep, dim3(3 * INNERc / 32, Dd / 32, DEPTHc), dim3(32, 8), 0, stream,
                       W_qkv, wt_qkv, Dd, 3 * INNERc);
    hipLaunchKernelGGL(k_wprep, dim3(Dd / 32, Dd / 32, DEPTHc), dim3(32, 8), 0, stream,
                       W_out, wt_out, Dd, Dd);
    hipLaunchKernelGGL(k_wprep_head, dim3(32, 24), dim3(32, 8), 0, stream,
                       W_head, wh_head);

    // 1. patchify + patch LN -> xh (f16)
    hipLaunchKernelGGL(k_patch_ln, dim3(Bc * NPc), dim3(256), 0, stream,
                       img, patch_g, patch_b, xh);
    // 2. patch GEMM (+b_patch) -> tmp fp32
    hipLaunchKernelGGL((k_hgemm<1, 0, float, 0>), dim3(6 * 49), dim3(256), 0, stream,
                       xh, wt_patch, b_patch, nullptr,
                       tmp, nullptr, nullptr, Bc * NPc, Dd, Dd);
    // 3. emb LN + cls concat + pos add -> x
    hipLaunchKernelGGL(k_embed, dim3(Bc * Nn), dim3(256), 0, stream,
                       tmp, cls, pos, emb_g, emb_b, x);

    const int Mrows = Bc * Nn;  // 6304
    for (int l = 0; l < DEPTHc; l++) {
        const float* g  = ln_g + (long)l * Dd;
        const float* bb = ln_b + (long)l * Dd;
        const half_t* Wq = wt_qkv + (long)l * 3 * INNERc * Dd;
        const half_t* Wo = wt_out + (long)l * Dd * Dd;
        const float* bo = b_out + (long)l * Dd;
        hipLaunchKernelGGL((k_ln<half_t>), dim3(Mrows), dim3(256), 0, stream,
                           x, g, bb, xh, (long)Dd, (long)Dd);
        // qkv GEMM; q/k head-major, V staged in LDS + written transposed coalesced
        hipLaunchKernelGGL((k_hgemm<0, 0, half_t, 1>), dim3(18 * 50), dim3(256), 0, stream,
                           xh, Wq, nullptr, nullptr,
                           qhb, khb, vtb, Mrows, 3 * INNERc, Dd);
        hipLaunchKernelGGL(k_stats, dim3(1352), dim3(256), 0, stream,
                           qhb, khb, (f32x4*)muG, (f32x4*)rsG);
        hipLaunchKernelGGL(k_attn2, dim3(4992), dim3(64), 0, stream,
                           qhb, khb, vtb, (const f32x4*)muG, (const f32x4*)rsG, xh);
        hipLaunchKernelGGL((k_hgemm<1, 1, float, 0>), dim3(6 * 50), dim3(256), 0, stream,
                           xh, Wo, bo, x,
                           x, nullptr, nullptr, Mrows, Dd, Dd);
    }
    // final LN (cls rows only) -> clsh f16
    hipLaunchKernelGGL((k_ln<half_t>), dim3(Bc), dim3(256), 0, stream,
                       x, fin_g, fin_b, clsh, (long)Nn * Dd, (long)Dd);
    // head GEMM: f16 dot per (row,col)
    hipLaunchKernelGGL(k_head, dim3(128), dim3(256), 0, stream,
                       clsh, wh_head, b_head, out);
}

// Round 15
// 1670.321 us; speedup vs baseline: 2.1947x; 1.0191x over previous
//
#include <hip/hip_runtime.h>
#include <math.h>

// ---------------- problem constants ----------------
constexpr int Bc = 32, Cch = 3, Hh = 224, Ww = 224, Pp = 16;
constexpr int Dd = 768, NH = 12, DHd = 64, INNERc = 768;
constexpr int DEPTHc = 12, NCLS = 1000;
constexpr int NPc = 196, Nn = 197, PD = 768;
constexpr float EPSf = 1e-5f;

typedef _Float16 half_t;
typedef __attribute__((ext_vector_type(8))) _Float16 half8;
typedef __attribute__((ext_vector_type(4))) float f32x4;
typedef __attribute__((ext_vector_type(4))) unsigned int uint32x4;

// ---------------- reduction helpers ----------------
__device__ __forceinline__ float wave_red_sum(float v) {
#pragma unroll
    for (int m = 32; m; m >>= 1) v += __shfl_xor(v, m);
    return v;
}

__device__ __forceinline__ void block_red2(float& s, float& s2, float* red) {
    s = wave_red_sum(s);
    s2 = wave_red_sum(s2);
    int wid = threadIdx.x >> 6, lane = threadIdx.x & 63;
    if (lane == 0) { red[wid] = s; red[4 + wid] = s2; }
    __syncthreads();
    s = red[0] + red[1] + red[2] + red[3];
    s2 = red[4] + red[5] + red[6] + red[7];
}

// ---------------- patchify + patch LN -> f16 ----------------
__global__ __launch_bounds__(256) void k_patch_ln(
        const float* __restrict__ img, const float* __restrict__ g,
        const float* __restrict__ bb, half_t* __restrict__ out) {
    int pid = blockIdx.x;
    int b = pid / NPc, n = pid % NPc;
    int ph = n / 14, pw = n % 14;
    int t = threadIdx.x;
    __shared__ float red[8];
    float v[3];
#pragma unroll
    for (int i = 0; i < 3; i++) {
        int d = t + i * 256;
        int c = d % 3, q = (d / 3) & 15, p = d / 48;
        v[i] = img[((long)(b * Cch + c) * Hh + ph * Pp + p) * Ww + pw * Pp + q];
    }
    float s = v[0] + v[1] + v[2];
    float s2 = v[0] * v[0] + v[1] * v[1] + v[2] * v[2];
    block_red2(s, s2, red);
    float mu = s * (1.f / PD);
    float var = s2 * (1.f / PD) - mu * mu;
    float r = rsqrtf(var + EPSf);
#pragma unroll
    for (int i = 0; i < 3; i++) {
        int d = t + i * 256;
        out[(long)pid * PD + d] = (half_t)((v[i] - mu) * r * g[d] + bb[d]);
    }
}

// ---------------- row LayerNorm (768 wide), templated output ----------------
template <typename T>
__global__ __launch_bounds__(256) void k_ln(
        const float* __restrict__ in, const float* __restrict__ g,
        const float* __restrict__ bb, T* __restrict__ out,
        long in_stride, long out_stride) {
    long row = blockIdx.x;
    const float* ip = in + row * in_stride;
    T* op = out + row * out_stride;
    int t = threadIdx.x;
    __shared__ float red[8];
    float v[3];
#pragma unroll
    for (int i = 0; i < 3; i++) v[i] = ip[t + i * 256];
    float s = v[0] + v[1] + v[2];
    float s2 = v[0] * v[0] + v[1] * v[1] + v[2] * v[2];
    block_red2(s, s2, red);
    float mu = s * (1.f / Dd);
    float var = s2 * (1.f / Dd) - mu * mu;
    float r = rsqrtf(var + EPSf);
#pragma unroll
    for (int i = 0; i < 3; i++) {
        int d = t + i * 256;
        op[d] = (T)((v[i] - mu) * r * g[d] + bb[d]);
    }
}

// ---------------- embed assemble: LN(tmp)+pos, cls+pos ----------------
__global__ __launch_bounds__(256) void k_embed(
        const float* __restrict__ tmp, const float* __restrict__ cls,
        const float* __restrict__ pos, const float* __restrict__ g,
        const float* __restrict__ bb, float* __restrict__ x) {
    int pid = blockIdx.x;
    int b = pid / Nn, n = pid % Nn;
    int t = threadIdx.x;
    float* xp = x + (long)pid * Dd;
    if (n == 0) {
#pragma unroll
        for (int i = 0; i < 3; i++) {
            int d = t + i * 256;
            xp[d] = cls[d] + pos[d];
        }
        return;
    }
    const float* ip = tmp + (long)(b * NPc + n - 1) * Dd;
    __shared__ float red[8];
    float v[3];
#pragma unroll
    for (int i = 0; i < 3; i++) v[i] = ip[t + i * 256];
    float s = v[0] + v[1] + v[2];
    float s2 = v[0] * v[0] + v[1] * v[1] + v[2] * v[2];
    block_red2(s, s2, red);
    float mu = s * (1.f / Dd);
    float var = s2 * (1.f / Dd) - mu * mu;
    float r = rsqrtf(var + EPSf);
#pragma unroll
    for (int i = 0; i < 3; i++) {
        int d = t + i * 256;
        xp[d] = (v[i] - mu) * r * g[d] + bb[d] + pos[(long)n * Dd + d];
    }
}

// ---------------- weight prep: fp32 W[K][N] -> f16 Wt[N][K] ----------------
__global__ __launch_bounds__(256) void k_wprep(
        const float* __restrict__ W, half_t* __restrict__ Wt, int K, int N) {
    W += (long)blockIdx.z * K * N;
    Wt += (long)blockIdx.z * K * N;
    __shared__ float tile[32][33];
    int n = blockIdx.x * 32 + threadIdx.x;
    int k0 = blockIdx.y * 32;
#pragma unroll
    for (int i = 0; i < 4; i++)
        tile[threadIdx.y + i * 8][threadIdx.x] = W[(long)(k0 + threadIdx.y + i * 8) * N + n];
    __syncthreads();
    int kk = k0 + threadIdx.x;
#pragma unroll
    for (int i = 0; i < 4; i++)
        Wt[(long)(blockIdx.x * 32 + threadIdx.y + i * 8) * K + kk] =
            (half_t)tile[threadIdx.x][threadIdx.y + i * 8];
}

// ---------------- head weight prep: fp32 [768][1000] -> f16 [1024][768] (pad 0) --------
__global__ __launch_bounds__(256) void k_wprep_head(
        const float* __restrict__ W, half_t* __restrict__ Wt) {
    __shared__ float tile[32][33];
    int n = blockIdx.x * 32 + threadIdx.x;
    int k0 = blockIdx.y * 32;
#pragma unroll
    for (int i = 0; i < 4; i++)
        tile[threadIdx.y + i * 8][threadIdx.x] =
            (n < NCLS) ? W[(long)(k0 + threadIdx.y + i * 8) * NCLS + n] : 0.f;
    __syncthreads();
    int kk = k0 + threadIdx.x;
#pragma unroll
    for (int i = 0; i < 4; i++)
        Wt[(long)(blockIdx.x * 32 + threadIdx.y + i * 8) * Dd + kk] =
            (half_t)tile[threadIdx.x][threadIdx.y + i * 8];
}

// ---------------- head GEMM: one thread per (row,col), f16 dot ----------------
__global__ __launch_bounds__(256) void k_head(
        const half_t* __restrict__ Ah, const half_t* __restrict__ Wh,
        const float* __restrict__ bias, float* __restrict__ out) {
    int idx = blockIdx.x * 256 + threadIdx.x;
    int row = idx >> 10, col = idx & 1023;
    if (col >= NCLS) return;
    const half_t* ap = Ah + (long)row * Dd;
    const half_t* wp = Wh + (long)col * Dd;
    float acc = 0.f;
#pragma unroll
    for (int k = 0; k < 96; k++) {
        half8 a = *(const half8*)&ap[k * 8];
        half8 w = *(const half8*)&wp[k * 8];
#pragma unroll
        for (int u = 0; u < 8; u++) acc += (float)a[u] * (float)w[u];
    }
    out[(long)row * NCLS + col] = acc + bias[col];
}

// ---------------- f16 MFMA GEMM ----------------
// Staging via global_load_lds width=16 (m97 structure): LDS dest linear
// (wave-uniform base + lane*16); global SOURCE pre-swizzled by chunk^(row&7)
// so the existing XOR-swizzled ds_read fragment path is unchanged (m173).
// OMODE=1 (qkv): C=q, C1=k head-major [b,h,n,64]; V third (n0>=1536) staged
//   TRANSPOSED in LDS then written lane-coalesced into Vt [b,h,64,224].
__device__ __forceinline__ half8 lds_frag(const uint32x4 (*L)[8], int row, int slot) {
    union { uint32x4 u; half8 h; } t;
    t.u = L[row][slot];
    return t.h;
}

__device__ __forceinline__ void gload16(const half_t* g, uint32x4* l) {
    __builtin_amdgcn_global_load_lds(
        (const __attribute__((address_space(1))) unsigned int*)g,
        (__attribute__((address_space(3))) unsigned int*)l,
        16, 0, 0);
}

template <int HASB, int HASR, typename CT, int OMODE>
__global__ __launch_bounds__(256, 2) void k_hgemm(
        const half_t* __restrict__ A, const half_t* __restrict__ Bt,
        const float* __restrict__ bias, const float* __restrict__ res,
        CT* __restrict__ C, CT* __restrict__ C1, half_t* __restrict__ Vt,
        int M, int N, int K) {
    __shared__ uint32x4 smem[2176];   // A[1024] | B[1024]; epilogue aliases half Cs
    uint32x4 (*As)[8] = (uint32x4(*)[8])smem;
    uint32x4 (*Bs)[8] = (uint32x4(*)[8])(smem + 1024);
    const int tid = threadIdx.x;
    const int nwg = gridDim.x;
    const int q8 = nwg >> 3, r8 = nwg & 7;
    const int xc = blockIdx.x & 7, oo = blockIdx.x >> 3;
    const int tile = (xc < r8 ? xc * (q8 + 1) : r8 * (q8 + 1) + (xc - r8) * q8) + oo;
    const int gx = N >> 7;
    const int n0 = (tile % gx) * 128, m0 = (tile / gx) * 128;
    const int lane = tid & 63, w = tid >> 6;
    const int wrr = (w >> 1) * 64, wcc = (w & 1) * 64;
    const int lrow = lane & 15, lgrp = lane >> 4;

    // staging: each wave owns 32 rows (4 calls x 8 rows); lane l covers
    // row (l>>3), slot (l&7) of the 1KB span. Source chunk pre-swizzled.
    int ldsOff[4];
    long gsA[4], gsB[4];
#pragma unroll
    for (int c = 0; c < 4; ++c) {
        int r = w * 32 + c * 8 + (lane >> 3);
        int chunk = (lane & 7) ^ (r & 7);
        ldsOff[c] = (w * 32 + c * 8) * 8;
        gsA[c] = (long)min(m0 + r, M - 1) * K + chunk * 8;
        gsB[c] = (long)(n0 + r) * K + chunk * 8;
    }

    f32x4 acc[4][4] = {};

#define STAGE(k0)                                         \
    {                                                     \
        _Pragma("unroll")                                 \
        for (int c = 0; c < 4; ++c) {                     \
            gload16(A + gsA[c] + (k0), smem + ldsOff[c]); \
            gload16(Bt + gsB[c] + (k0), smem + 1024 + ldsOff[c]); \
        }                                                 \
    }

    STAGE(0);
    __syncthreads();

    const int nst = K >> 6;
    for (int t = 0; t < nst; ++t) {
#pragma unroll
        for (int kh = 0; kh < 2; ++kh) {
            half8 af[4], bf[4];
#pragma unroll
            for (int i2 = 0; i2 < 4; ++i2) {
                int m = wrr + i2 * 16 + lrow;
                af[i2] = lds_frag(As, m, (kh * 4 + lgrp) ^ (m & 7));
                int n = wcc + i2 * 16 + lrow;
                bf[i2] = lds_frag(Bs, n, (kh * 4 + lgrp) ^ (n & 7));
            }
#pragma unroll
            for (int i2 = 0; i2 < 4; ++i2)
#pragma unroll
                for (int j2 = 0; j2 < 4; ++j2)
                    acc[i2][j2] = __builtin_amdgcn_mfma_f32_16x16x32_f16(af[i2], bf[j2], acc[i2][j2], 0, 0, 0);
        }
        if (t + 1 < nst) {
            __syncthreads();            // all reads of current tile done
            STAGE((t + 1) << 6);        // async global->LDS
            __syncthreads();            // loads complete (vmcnt drained)
        }
    }
#undef STAGE

    if constexpr (sizeof(CT) == 2) {
        if constexpr (OMODE == 1) {
            if (n0 >= 1536) {
                // V third: stage TRANSPOSED in LDS (Cs[col][token], stride 136),
                // then lane-coalesced scalar stores (consecutive lanes = consecutive nn).
                __syncthreads();
                half_t* Cs = (half_t*)smem;
#pragma unroll
                for (int i2 = 0; i2 < 4; ++i2)
#pragma unroll
                    for (int j2 = 0; j2 < 4; ++j2) {
                        int colc = wcc + j2 * 16 + lrow;
#pragma unroll
                        for (int q = 0; q < 4; ++q) {
                            int r = wrr + i2 * 16 + lgrp * 4 + q;
                            Cs[colc * 136 + r] = (half_t)acc[i2][j2][q];
                        }
                    }
                __syncthreads();
                const int rr = tid & 127;      // token offset (lane-consecutive)
                const int cbase = (tid >> 7) * 64;
                int token = m0 + rr;
                bool ok = token < M;
                int b = 0, nn = 0;
                if (ok) { b = token / Nn; nn = token - b * Nn; }
#pragma unroll
                for (int cc = 0; cc < 64; ++cc) {
                    int c = cbase + cc;
                    int rem = n0 + c - 1536;
                    int h = rem >> 6, d = rem & 63;
                    if (ok)
                        Vt[((long)(b * NH + h) * 64 + d) * 224 + nn] = Cs[c * 136 + rr];
                }
                return;
            }
        }
        __syncthreads();
        half_t* Cs = (half_t*)smem;
#pragma unroll
        for (int i2 = 0; i2 < 4; ++i2)
#pragma unroll
            for (int j2 = 0; j2 < 4; ++j2) {
                int colc = wcc + j2 * 16 + lrow;
                float bv = HASB ? bias[n0 + colc] : 0.f;
#pragma unroll
                for (int q = 0; q < 4; ++q) {
                    int r = wrr + i2 * 16 + lgrp * 4 + q;
                    Cs[r * 136 + colc] = (half_t)(acc[i2][j2][q] + bv);
                }
            }
        __syncthreads();
#pragma unroll
        for (int it = 0; it < 8; ++it) {
            int idx = tid + it * 256;
            int row = idx >> 4, cu = idx & 15;
            int token = m0 + row;
            if (token < M) {
                uint32x4 val = *(const uint32x4*)(Cs + row * 136 + cu * 8);
                if constexpr (OMODE == 1) {
                    int gc = n0 + cu * 8;
                    int which = gc >= 768 ? 1 : 0;
                    int rem = gc - which * 768;
                    int h = rem >> 6, d = rem & 63;
                    int b = token / Nn, nn = token - b * Nn;
                    CT* dst = (which == 0 ? C : C1);
                    __builtin_nontemporal_store(val,
                        (uint32x4*)(dst + (((long)(b * NH + h) * Nn + nn) << 6) + d));
                } else {
                    __builtin_nontemporal_store(val,
                        (uint32x4*)(C + (long)token * N + n0 + cu * 8));
                }
            }
        }
    } else {
#pragma unroll
        for (int i2 = 0; i2 < 4; ++i2)
#pragma unroll
            for (int j2 = 0; j2 < 4; ++j2) {
                int colc = n0 + wcc + j2 * 16 + lrow;
                float bv = HASB ? bias[colc] : 0.f;
#pragma unroll
                for (int q = 0; q < 4; ++q) {
                    int r = m0 + wrr + i2 * 16 + lgrp * 4 + q;
                    if (r < M) {
                        float v = acc[i2][j2][q] + bv;
                        if (HASR) v += res[(long)r * N + colc];
                        __builtin_nontemporal_store(v, &C[(long)r * N + colc]);
                    }
                }
            }
    }
}

// ---------------- attention stats: cross-head mu & rsqrt(var), fragment layout --------
// 2 waves per task (6 heads each); register partials combined via one LDS pass.
__global__ __launch_bounds__(256) void k_stats(
        const half_t* __restrict__ qh, const half_t* __restrict__ kh,
        f32x4* __restrict__ muT, f32x4* __restrict__ rsT) {
    __shared__ f32x4 redv[2][64], redq[2][64];
    const int blk = (blockIdx.x & 7) * 338 + (blockIdx.x >> 3);   // 2704 = 8*338
    const int w = threadIdx.x >> 6, lane = threadIdx.x & 63;
    const int ti = w >> 1, hh2 = w & 1;
    const int task = blk * 2 + ti;                                 // 5408 tasks
    const int b = task / 169, r = task % 169;
    const int it = r / 13, jt = r % 13;
    const int lrow = lane & 15, lg = lane >> 4;
    const int i0 = it * 16, j0 = jt * 16;
    const int arow = min(i0 + lrow, Nn - 1);
    const int jr = min(j0 + lrow, Nn - 1);
    const int hbase = b * NH + hh2 * 6;

    float sv[4] = {}, sq[4] = {};
#pragma unroll
    for (int h = 0; h < 6; h++) {
        const half_t* Qp = qh + ((long)(hbase + h) * Nn) * 64;
        const half_t* Kp = kh + ((long)(hbase + h) * Nn) * 64;
        half8 af0 = *(const half8*)&Qp[(long)arow * 64 + lg * 8];
        half8 af1 = *(const half8*)&Qp[(long)arow * 64 + 32 + lg * 8];
        half8 bf0 = *(const half8*)&Kp[(long)jr * 64 + lg * 8];
        half8 bf1 = *(const half8*)&Kp[(long)jr * 64 + 32 + lg * 8];
        f32x4 acc = {};
        acc = __builtin_amdgcn_mfma_f32_16x16x32_f16(af0, bf0, acc, 0, 0, 0);
        acc = __builtin_amdgcn_mfma_f32_16x16x32_f16(af1, bf1, acc, 0, 0, 0);
#pragma unroll
        for (int q = 0; q < 4; q++) { sv[q] += acc[q]; sq[q] += acc[q] * acc[q]; }
    }
    if (hh2 == 1) {
        f32x4 a, b2;
#pragma unroll
        for (int q = 0; q < 4; q++) { a[q] = sv[q]; b2[q] = sq[q]; }
        redv[ti][lane] = a;
        redq[ti][lane] = b2;
    }
    __syncthreads();
    if (hh2 == 0) {
        f32x4 a = redv[ti][lane], b2 = redq[ti][lane];
        f32x4 muv, rsv;
#pragma unroll
        for (int q = 0; q < 4; q++) {
            float svt = sv[q] + a[q];
            float sqt = sq[q] + b2[q];
            float mu = svt * (1.f / NH);
            float var = (sqt - svt * mu) * (1.f / (NH - 1));
            muv[q] = mu;
            rsv[q] = rsqrtf(var);
        }
        long idx = ((long)(b * 13 + it) * 13 + jt) * 64 + lane;
        muT[idx] = muv;
        rsT[idx] = rsv;
    }
}

// ---------------- attention per head: S recompute + z-score + softmax + PV ----------------
// 128 threads = 2 waves per (b,h,i-tile): wave0 jt 0..6, wave1 jt 7..12;
// max/sum exchanged via LDS; PV split by output d-tile (wave0 dt 0-1, wave1 dt 2-3).
__global__ __launch_bounds__(128) void k_attn2(
        const half_t* __restrict__ qh, const half_t* __restrict__ kh,
        const half_t* __restrict__ vt, const f32x4* __restrict__ muT,
        const f32x4* __restrict__ rsT, half_t* __restrict__ o) {
    __shared__ half_t PB[16][232];
    __shared__ float xmx[2][16], xsm[2][16];
    const int tile = (blockIdx.x & 7) * 624 + (blockIdx.x >> 3);  // 4992 = 8*624
    const int bh = tile / 13, it = tile % 13;
    const int b = bh / NH, h = bh % NH;
    const int i0 = it * 16;
    const int tid = threadIdx.x;
    const int wv = tid >> 6, lane = tid & 63;
    const int lrow = lane & 15, lg = lane >> 4;
    const int arow = min(i0 + lrow, Nn - 1);
    const int jtbase = wv * 7;           // wv0: jt 0..6, wv1: jt 7..12
    const int njt = 7 - wv;              // 7 or 6

    if (wv == 0) {
        // zero pad cols 208..223
        for (int idx = lane; idx < 128; idx += 64) {
            int rr = idx >> 3, u = idx & 7;
            *(unsigned int*)&PB[rr][208 + u * 2] = 0u;
        }
    }

    const half_t* Qp = qh + ((long)bh * Nn) * 64;
    const half_t* Kp = kh + ((long)bh * Nn) * 64;
    half8 af0 = *(const half8*)&Qp[(long)arow * 64 + lg * 8];
    half8 af1 = *(const half8*)&Qp[(long)arow * 64 + 32 + lg * 8];
    const f32x4* muB = muT + ((long)(b * 13 + it) * 13) * 64 + lane;
    const f32x4* rsB = rsT + ((long)(b * 13 + it) * 13) * 64 + lane;

    float ez[7][4];
    float mx[4] = {-1e30f, -1e30f, -1e30f, -1e30f};
#pragma unroll
    for (int jj = 0; jj < 7; jj++) {
        if (jj < njt) {
            int jt = jtbase + jj;
            int jr = min(jt * 16 + lrow, Nn - 1);
            half8 bf0 = *(const half8*)&Kp[(long)jr * 64 + lg * 8];
            half8 bf1 = *(const half8*)&Kp[(long)jr * 64 + 32 + lg * 8];
            f32x4 acc = {};
            acc = __builtin_amdgcn_mfma_f32_16x16x32_f16(af0, bf0, acc, 0, 0, 0);
            acc = __builtin_amdgcn_mfma_f32_16x16x32_f16(af1, bf1, acc, 0, 0, 0);
            f32x4 mu4 = muB[jt * 64];
            f32x4 rs4 = rsB[jt * 64];
            bool joob = (jt * 16 + lrow) > Nn - 1;
#pragma unroll
            for (int q = 0; q < 4; q++) {
                float z = (acc[q] - mu4[q]) * rs4[q];
                if (joob) z = -1e30f;
                ez[jj][q] = z;
                mx[q] = fmaxf(mx[q], z);
            }
        }
    }
#pragma unroll
    for (int st = 1; st <= 8; st <<= 1)
#pragma unroll
        for (int q = 0; q < 4; q++) mx[q] = fmaxf(mx[q], __shfl_xor(mx[q], st));
    if (lrow == 0) {
#pragma unroll
        for (int q = 0; q < 4; q++) xmx[wv][lg * 4 + q] = mx[q];
    }
    __syncthreads();
    float cmx[4];
#pragma unroll
    for (int q = 0; q < 4; q++)
        cmx[q] = fmaxf(xmx[0][lg * 4 + q], xmx[1][lg * 4 + q]);
    float sm[4] = {0.f, 0.f, 0.f, 0.f};
#pragma unroll
    for (int jj = 0; jj < 7; jj++) {
        if (jj < njt) {
#pragma unroll
            for (int q = 0; q < 4; q++) {
                float e = __expf(ez[jj][q] - cmx[q]);
                ez[jj][q] = e;
                sm[q] += e;
            }
        }
    }
#pragma unroll
    for (int st = 1; st <= 8; st <<= 1)
#pragma unroll
        for (int q = 0; q < 4; q++) sm[q] += __shfl_xor(sm[q], st);
    if (lrow == 0) {
#pragma unroll
        for (int q = 0; q < 4; q++) xsm[wv][lg * 4 + q] = sm[q];
    }
    __syncthreads();
    float inv[4];
#pragma unroll
    for (int q = 0; q < 4; q++)
        inv[q] = 1.f / (xsm[0][lg * 4 + q] + xsm[1][lg * 4 + q]);
#pragma unroll
    for (int jj = 0; jj < 7; jj++) {
        if (jj < njt) {
#pragma unroll
            for (int q = 0; q < 4; q++)
                PB[lg * 4 + q][(jtbase + jj) * 16 + lrow] = (half_t)(ez[jj][q] * inv[q]);
        }
    }
    __syncthreads();

    // PV: wave wv computes output d-tiles wv*2 .. wv*2+1
    const half_t* Vtp = vt + ((long)bh * 64) * 224;
#pragma unroll
    for (int dd = 0; dd < 2; dd++) {
        int dt = wv * 2 + dd;
        f32x4 oacc = {};
#pragma unroll
        for (int kt = 0; kt < 7; kt++) {
            half8 pa = *(const half8*)&PB[lrow][kt * 32 + lg * 8];
            half8 vb = *(const half8*)&Vtp[(long)(dt * 16 + lrow) * 224 + kt * 32 + lg * 8];
            oacc = __builtin_amdgcn_mfma_f32_16x16x32_f16(pa, vb, oacc, 0, 0, 0);
        }
#pragma unroll
        for (int q = 0; q < 4; q++) {
            int i = i0 + lg * 4 + q;
            if (i < Nn)
                o[((long)(b * Nn) + i) * INNERc + h * 64 + dt * 16 + lrow] = (half_t)oacc[q];
        }
    }
}

// ---------------- host launcher ----------------
extern "C" void kernel_launch(void* const* d_in, const int* in_sizes, int n_in,
                              void* d_out, int out_size, void* d_ws, size_t ws_size,
                              hipStream_t stream) {
    const float* img     = (const float*)d_in[0];
    const float* patch_g = (const float*)d_in[2];
    const float* patch_b = (const float*)d_in[3];
    const float* W_patch = (const float*)d_in[4];
    const float* b_patch = (const float*)d_in[5];
    const float* emb_g   = (const float*)d_in[6];
    const float* emb_b   = (const float*)d_in[7];
    const float* pos     = (const float*)d_in[8];
    const float* cls     = (const float*)d_in[9];
    const float* ln_g    = (const float*)d_in[10];
    const float* ln_b    = (const float*)d_in[11];
    const float* W_qkv   = (const float*)d_in[12];
    const float* W_out   = (const float*)d_in[13];
    const float* b_out   = (const float*)d_in[14];
    const float* fin_g   = (const float*)d_in[15];
    const float* fin_b   = (const float*)d_in[16];
    const float* W_head  = (const float*)d_in[17];
    const float* b_head  = (const float*)d_in[18];
    float* out = (float*)d_out;

    const long SZ_XD  = (long)Bc * Nn * Dd;            // 4,841,472
    const long SZ_HD  = (long)Bc * NH * Nn * DHd;      // 4,841,472
    const long SZ_VT  = (long)Bc * NH * 64 * 224;      // 5,505,024
    const long SZ_TMP = (long)Bc * NPc * Dd;
    const long SZ_MU  = (long)Bc * 169 * 256 + 1024;   // fragment-layout stats

    float* x    = (float*)d_ws;
    float* tmp  = x + SZ_XD;
    float* muG  = tmp + SZ_TMP;
    float* rsG  = muG + SZ_MU;
    half_t* xh       = (half_t*)(rsG + SZ_MU);
    half_t* qhb      = xh + SZ_XD;
    half_t* khb      = qhb + SZ_HD;
    half_t* vtb      = khb + SZ_HD;
    half_t* clsh     = vtb + SZ_VT;                         // 32x768 f16
    half_t* wh_head  = clsh + 32 * Dd;                      // 1024x768 f16
    half_t* wt_patch = wh_head + 1024 * Dd;
    half_t* wt_qkv   = wt_patch + (long)Dd * Dd;
    half_t* wt_out   = wt_qkv + (long)DEPTHc * 3 * INNERc * Dd;

    // ---- weight prep ----
    hipLaunchKernelGGL(k_wprep, dim3(Dd / 32, Dd / 32, 1), dim3(32, 8), 0, stream,
                       W_patch, wt_patch, Dd, Dd);
    hipLaunchKernelGGL(k_wprep, dim3(3 * INNERc / 32, Dd / 32, DEPTHc), dim3(32, 8), 0, stream,
                       W_qkv, wt_qkv, Dd, 3 * INNERc);
    hipLaunchKernelGGL(k_wprep, dim3(Dd / 32, Dd / 32, DEPTHc), dim3(32, 8), 0, stream,
                       W_out, wt_out, Dd, Dd);
    hipLaunchKernelGGL(k_wprep_head, dim3(32, 24), dim3(32, 8), 0, stream,
                       W_head, wh_head);

    // 1. patchify + patch LN -> xh (f16)
    hipLaunchKernelGGL(k_patch_ln, dim3(Bc * NPc), dim3(256), 0, stream,
                       img, patch_g, patch_b, xh);
    // 2. patch GEMM (+b_patch) -> tmp fp32
    hipLaunchKernelGGL((k_hgemm<1, 0, float, 0>), dim3(6 * 49), dim3(256), 0, stream,
                       xh, wt_patch, b_patch, nullptr,
                       tmp, nullptr, nullptr, Bc * NPc, Dd, Dd);
    // 3. emb LN + cls concat + pos add -> x
    hipLaunchKernelGGL(k_embed, dim3(Bc * Nn), dim3(256), 0, stream,
                       tmp, cls, pos, emb_g, emb_b, x);

    const int Mrows = Bc * Nn;  // 6304
    for (int l = 0; l < DEPTHc; l++) {
        const float* g  = ln_g + (long)l * Dd;
        const float* bb = ln_b + (long)l * Dd;
        const half_t* Wq = wt_qkv + (long)l * 3 * INNERc * Dd;
        const half_t* Wo = wt_out + (long)l * Dd * Dd;
        const float* bo = b_out + (long)l * Dd;
        hipLaunchKernelGGL((k_ln<half_t>), dim3(Mrows), dim3(256), 0, stream,
                           x, g, bb, xh, (long)Dd, (long)Dd);
        // qkv GEMM; q/k head-major, V staged in LDS + written transposed coalesced
        hipLaunchKernelGGL((k_hgemm<0, 0, half_t, 1>), dim3(18 * 50), dim3(256), 0, stream,
                           xh, Wq, nullptr, nullptr,
                           qhb, khb, vtb, Mrows, 3 * INNERc, Dd);
        hipLaunchKernelGGL(k_stats, dim3(2704), dim3(256), 0, stream,
                           qhb, khb, (f32x4*)muG, (f32x4*)rsG);
        hipLaunchKernelGGL(k_attn2, dim3(4992), dim3(128), 0, stream,
                           qhb, khb, vtb, (const f32x4*)muG, (const f32x4*)rsG, xh);
        hipLaunchKernelGGL((k_hgemm<1, 1, float, 0>), dim3(6 * 50), dim3(256), 0, stream,
                           xh, Wo, bo, x,
                           x, nullptr, nullptr, Mrows, Dd, Dd);
    }
    // final LN (cls rows only) -> clsh f16
    hipLaunchKernelGGL((k_ln<half_t>), dim3(Bc), dim3(256), 0, stream,
                       x, fin_g, fin_b, clsh, (long)Nn * Dd, (long)Dd);
    // head GEMM: f16 dot per (row,col)
    hipLaunchKernelGGL(k_head, dim3(128), dim3(256), 0, stream,
                       clsh, wh_head, b_head, out);
}

// Round 16
// 1585.265 us; speedup vs baseline: 2.3125x; 1.0537x over previous
//
#include <hip/hip_runtime.h>
#include <math.h>

// ---------------- problem constants ----------------
constexpr int Bc = 32, Cch = 3, Hh = 224, Ww = 224, Pp = 16;
constexpr int Dd = 768, NH = 12, DHd = 64, INNERc = 768;
constexpr int DEPTHc = 12, NCLS = 1000;
constexpr int NPc = 196, Nn = 197, PD = 768;
constexpr float EPSf = 1e-5f;

typedef _Float16 half_t;
typedef __attribute__((ext_vector_type(8))) _Float16 half8;
typedef __attribute__((ext_vector_type(4))) float f32x4;
typedef __attribute__((ext_vector_type(4))) unsigned int uint32x4;

// ---------------- reduction helpers ----------------
__device__ __forceinline__ float wave_red_sum(float v) {
#pragma unroll
    for (int m = 32; m; m >>= 1) v += __shfl_xor(v, m);
    return v;
}

__device__ __forceinline__ void block_red2(float& s, float& s2, float* red) {
    s = wave_red_sum(s);
    s2 = wave_red_sum(s2);
    int wid = threadIdx.x >> 6, lane = threadIdx.x & 63;
    if (lane == 0) { red[wid] = s; red[4 + wid] = s2; }
    __syncthreads();
    s = red[0] + red[1] + red[2] + red[3];
    s2 = red[4] + red[5] + red[6] + red[7];
}

// ---------------- patchify + patch LN -> f16 ----------------
__global__ __launch_bounds__(256) void k_patch_ln(
        const float* __restrict__ img, const float* __restrict__ g,
        const float* __restrict__ bb, half_t* __restrict__ out) {
    int pid = blockIdx.x;
    int b = pid / NPc, n = pid % NPc;
    int ph = n / 14, pw = n % 14;
    int t = threadIdx.x;
    __shared__ float red[8];
    float v[3];
#pragma unroll
    for (int i = 0; i < 3; i++) {
        int d = t + i * 256;
        int c = d % 3, q = (d / 3) & 15, p = d / 48;
        v[i] = img[((long)(b * Cch + c) * Hh + ph * Pp + p) * Ww + pw * Pp + q];
    }
    float s = v[0] + v[1] + v[2];
    float s2 = v[0] * v[0] + v[1] * v[1] + v[2] * v[2];
    block_red2(s, s2, red);
    float mu = s * (1.f / PD);
    float var = s2 * (1.f / PD) - mu * mu;
    float r = rsqrtf(var + EPSf);
#pragma unroll
    for (int i = 0; i < 3; i++) {
        int d = t + i * 256;
        out[(long)pid * PD + d] = (half_t)((v[i] - mu) * r * g[d] + bb[d]);
    }
}

// ---------------- row LayerNorm (768 wide), templated output ----------------
template <typename T>
__global__ __launch_bounds__(256) void k_ln(
        const float* __restrict__ in, const float* __restrict__ g,
        const float* __restrict__ bb, T* __restrict__ out,
        long in_stride, long out_stride) {
    long row = blockIdx.x;
    const float* ip = in + row * in_stride;
    T* op = out + row * out_stride;
    int t = threadIdx.x;
    __shared__ float red[8];
    float v[3];
#pragma unroll
    for (int i = 0; i < 3; i++) v[i] = ip[t + i * 256];
    float s = v[0] + v[1] + v[2];
    float s2 = v[0] * v[0] + v[1] * v[1] + v[2] * v[2];
    block_red2(s, s2, red);
    float mu = s * (1.f / Dd);
    float var = s2 * (1.f / Dd) - mu * mu;
    float r = rsqrtf(var + EPSf);
#pragma unroll
    for (int i = 0; i < 3; i++) {
        int d = t + i * 256;
        op[d] = (T)((v[i] - mu) * r * g[d] + bb[d]);
    }
}

// ---------------- embed assemble: LN(tmp)+pos, cls+pos ----------------
__global__ __launch_bounds__(256) void k_embed(
        const float* __restrict__ tmp, const float* __restrict__ cls,
        const float* __restrict__ pos, const float* __restrict__ g,
        const float* __restrict__ bb, float* __restrict__ x) {
    int pid = blockIdx.x;
    int b = pid / Nn, n = pid % Nn;
    int t = threadIdx.x;
    float* xp = x + (long)pid * Dd;
    if (n == 0) {
#pragma unroll
        for (int i = 0; i < 3; i++) {
            int d = t + i * 256;
            xp[d] = cls[d] + pos[d];
        }
        return;
    }
    const float* ip = tmp + (long)(b * NPc + n - 1) * Dd;
    __shared__ float red[8];
    float v[3];
#pragma unroll
    for (int i = 0; i < 3; i++) v[i] = ip[t + i * 256];
    float s = v[0] + v[1] + v[2];
    float s2 = v[0] * v[0] + v[1] * v[1] + v[2] * v[2];
    block_red2(s, s2, red);
    float mu = s * (1.f / Dd);
    float var = s2 * (1.f / Dd) - mu * mu;
    float r = rsqrtf(var + EPSf);
#pragma unroll
    for (int i = 0; i < 3; i++) {
        int d = t + i * 256;
        xp[d] = (v[i] - mu) * r * g[d] + bb[d] + pos[(long)n * Dd + d];
    }
}

// ---------------- weight prep: fp32 W[K][N] -> f16 Wt[N][K] ----------------
__global__ __launch_bounds__(256) void k_wprep(
        const float* __restrict__ W, half_t* __restrict__ Wt, int K, int N) {
    W += (long)blockIdx.z * K * N;
    Wt += (long)blockIdx.z * K * N;
    __shared__ float tile[32][33];
    int n = blockIdx.x * 32 + threadIdx.x;
    int k0 = blockIdx.y * 32;
#pragma unroll
    for (int i = 0; i < 4; i++)
        tile[threadIdx.y + i * 8][threadIdx.x] = W[(long)(k0 + threadIdx.y + i * 8) * N + n];
    __syncthreads();
    int kk = k0 + threadIdx.x;
#pragma unroll
    for (int i = 0; i < 4; i++)
        Wt[(long)(blockIdx.x * 32 + threadIdx.y + i * 8) * K + kk] =
            (half_t)tile[threadIdx.x][threadIdx.y + i * 8];
}

// ---------------- head weight prep: fp32 [768][1000] -> f16 [1024][768] (pad 0) --------
__global__ __launch_bounds__(256) void k_wprep_head(
        const float* __restrict__ W, half_t* __restrict__ Wt) {
    __shared__ float tile[32][33];
    int n = blockIdx.x * 32 + threadIdx.x;
    int k0 = blockIdx.y * 32;
#pragma unroll
    for (int i = 0; i < 4; i++)
        tile[threadIdx.y + i * 8][threadIdx.x] =
            (n < NCLS) ? W[(long)(k0 + threadIdx.y + i * 8) * NCLS + n] : 0.f;
    __syncthreads();
    int kk = k0 + threadIdx.x;
#pragma unroll
    for (int i = 0; i < 4; i++)
        Wt[(long)(blockIdx.x * 32 + threadIdx.y + i * 8) * Dd + kk] =
            (half_t)tile[threadIdx.x][threadIdx.y + i * 8];
}

// ---------------- head GEMM: one thread per (row,col), f16 dot ----------------
__global__ __launch_bounds__(256) void k_head(
        const half_t* __restrict__ Ah, const half_t* __restrict__ Wh,
        const float* __restrict__ bias, float* __restrict__ out) {
    int idx = blockIdx.x * 256 + threadIdx.x;
    int row = idx >> 10, col = idx & 1023;
    if (col >= NCLS) return;
    const half_t* ap = Ah + (long)row * Dd;
    const half_t* wp = Wh + (long)col * Dd;
    float acc = 0.f;
#pragma unroll
    for (int k = 0; k < 96; k++) {
        half8 a = *(const half8*)&ap[k * 8];
        half8 w = *(const half8*)&wp[k * 8];
#pragma unroll
        for (int u = 0; u < 8; u++) acc += (float)a[u] * (float)w[u];
    }
    out[(long)row * NCLS + col] = acc + bias[col];
}

// ---------------- f16 MFMA GEMM ----------------
// Staging via global_load_lds width=16 (m97 structure): LDS dest linear
// (wave-uniform base + lane*16); global SOURCE pre-swizzled by chunk^(row&7)
// so the existing XOR-swizzled ds_read fragment path is unchanged (m173).
// OMODE=1 (qkv): C=q, C1=k head-major [b,h,n,64]; V third (n0>=1536) staged
//   TRANSPOSED in LDS then written lane-coalesced into Vt [b,h,64,224].
__device__ __forceinline__ half8 lds_frag(const uint32x4 (*L)[8], int row, int slot) {
    union { uint32x4 u; half8 h; } t;
    t.u = L[row][slot];
    return t.h;
}

__device__ __forceinline__ void gload16(const half_t* g, uint32x4* l) {
    __builtin_amdgcn_global_load_lds(
        (const __attribute__((address_space(1))) unsigned int*)g,
        (__attribute__((address_space(3))) unsigned int*)l,
        16, 0, 0);
}

template <int HASB, int HASR, typename CT, int OMODE>
__global__ __launch_bounds__(256, 2) void k_hgemm(
        const half_t* __restrict__ A, const half_t* __restrict__ Bt,
        const float* __restrict__ bias, const float* __restrict__ res,
        CT* __restrict__ C, CT* __restrict__ C1, half_t* __restrict__ Vt,
        int M, int N, int K) {
    __shared__ uint32x4 smem[2176];   // A[1024] | B[1024]; epilogue aliases half Cs
    uint32x4 (*As)[8] = (uint32x4(*)[8])smem;
    uint32x4 (*Bs)[8] = (uint32x4(*)[8])(smem + 1024);
    const int tid = threadIdx.x;
    const int nwg = gridDim.x;
    const int q8 = nwg >> 3, r8 = nwg & 7;
    const int xc = blockIdx.x & 7, oo = blockIdx.x >> 3;
    const int tile = (xc < r8 ? xc * (q8 + 1) : r8 * (q8 + 1) + (xc - r8) * q8) + oo;
    const int gx = N >> 7;
    const int n0 = (tile % gx) * 128, m0 = (tile / gx) * 128;
    const int lane = tid & 63, w = tid >> 6;
    const int wrr = (w >> 1) * 64, wcc = (w & 1) * 64;
    const int lrow = lane & 15, lgrp = lane >> 4;

    // staging: each wave owns 32 rows (4 calls x 8 rows); lane l covers
    // row (l>>3), slot (l&7) of the 1KB span. Source chunk pre-swizzled.
    int ldsOff[4];
    long gsA[4], gsB[4];
#pragma unroll
    for (int c = 0; c < 4; ++c) {
        int r = w * 32 + c * 8 + (lane >> 3);
        int chunk = (lane & 7) ^ (r & 7);
        ldsOff[c] = (w * 32 + c * 8) * 8;
        gsA[c] = (long)min(m0 + r, M - 1) * K + chunk * 8;
        gsB[c] = (long)(n0 + r) * K + chunk * 8;
    }

    f32x4 acc[4][4] = {};

#define STAGE(k0)                                         \
    {                                                     \
        _Pragma("unroll")                                 \
        for (int c = 0; c < 4; ++c) {                     \
            gload16(A + gsA[c] + (k0), smem + ldsOff[c]); \
            gload16(Bt + gsB[c] + (k0), smem + 1024 + ldsOff[c]); \
        }                                                 \
    }

    STAGE(0);
    __syncthreads();

    const int nst = K >> 6;
    for (int t = 0; t < nst; ++t) {
#pragma unroll
        for (int kh = 0; kh < 2; ++kh) {
            half8 af[4], bf[4];
#pragma unroll
            for (int i2 = 0; i2 < 4; ++i2) {
                int m = wrr + i2 * 16 + lrow;
                af[i2] = lds_frag(As, m, (kh * 4 + lgrp) ^ (m & 7));
                int n = wcc + i2 * 16 + lrow;
                bf[i2] = lds_frag(Bs, n, (kh * 4 + lgrp) ^ (n & 7));
            }
#pragma unroll
            for (int i2 = 0; i2 < 4; ++i2)
#pragma unroll
                for (int j2 = 0; j2 < 4; ++j2)
                    acc[i2][j2] = __builtin_amdgcn_mfma_f32_16x16x32_f16(af[i2], bf[j2], acc[i2][j2], 0, 0, 0);
        }
        if (t + 1 < nst) {
            __syncthreads();            // all reads of current tile done
            STAGE((t + 1) << 6);        // async global->LDS
            __syncthreads();            // loads complete (vmcnt drained)
        }
    }
#undef STAGE

    if constexpr (sizeof(CT) == 2) {
        if constexpr (OMODE == 1) {
            if (n0 >= 1536) {
                // V third: stage TRANSPOSED in LDS (Cs[col][token], stride 136),
                // then lane-coalesced scalar stores (consecutive lanes = consecutive nn).
                __syncthreads();
                half_t* Cs = (half_t*)smem;
#pragma unroll
                for (int i2 = 0; i2 < 4; ++i2)
#pragma unroll
                    for (int j2 = 0; j2 < 4; ++j2) {
                        int colc = wcc + j2 * 16 + lrow;
#pragma unroll
                        for (int q = 0; q < 4; ++q) {
                            int r = wrr + i2 * 16 + lgrp * 4 + q;
                            Cs[colc * 136 + r] = (half_t)acc[i2][j2][q];
                        }
                    }
                __syncthreads();
                const int rr = tid & 127;      // token offset (lane-consecutive)
                const int cbase = (tid >> 7) * 64;
                int token = m0 + rr;
                bool ok = token < M;
                int b = 0, nn = 0;
                if (ok) { b = token / Nn; nn = token - b * Nn; }
#pragma unroll
                for (int cc = 0; cc < 64; ++cc) {
                    int c = cbase + cc;
                    int rem = n0 + c - 1536;
                    int h = rem >> 6, d = rem & 63;
                    if (ok)
                        Vt[((long)(b * NH + h) * 64 + d) * 224 + nn] = Cs[c * 136 + rr];
                }
                return;
            }
        }
        __syncthreads();
        half_t* Cs = (half_t*)smem;
#pragma unroll
        for (int i2 = 0; i2 < 4; ++i2)
#pragma unroll
            for (int j2 = 0; j2 < 4; ++j2) {
                int colc = wcc + j2 * 16 + lrow;
                float bv = HASB ? bias[n0 + colc] : 0.f;
#pragma unroll
                for (int q = 0; q < 4; ++q) {
                    int r = wrr + i2 * 16 + lgrp * 4 + q;
                    Cs[r * 136 + colc] = (half_t)(acc[i2][j2][q] + bv);
                }
            }
        __syncthreads();
#pragma unroll
        for (int it = 0; it < 8; ++it) {
            int idx = tid + it * 256;
            int row = idx >> 4, cu = idx & 15;
            int token = m0 + row;
            if (token < M) {
                uint32x4 val = *(const uint32x4*)(Cs + row * 136 + cu * 8);
                if constexpr (OMODE == 1) {
                    int gc = n0 + cu * 8;
                    int which = gc >= 768 ? 1 : 0;
                    int rem = gc - which * 768;
                    int h = rem >> 6, d = rem & 63;
                    int b = token / Nn, nn = token - b * Nn;
                    CT* dst = (which == 0 ? C : C1);
                    __builtin_nontemporal_store(val,
                        (uint32x4*)(dst + (((long)(b * NH + h) * Nn + nn) << 6) + d));
                } else {
                    __builtin_nontemporal_store(val,
                        (uint32x4*)(C + (long)token * N + n0 + cu * 8));
                }
            }
        }
    } else {
#pragma unroll
        for (int i2 = 0; i2 < 4; ++i2)
#pragma unroll
            for (int j2 = 0; j2 < 4; ++j2) {
                int colc = n0 + wcc + j2 * 16 + lrow;
                float bv = HASB ? bias[colc] : 0.f;
#pragma unroll
                for (int q = 0; q < 4; ++q) {
                    int r = m0 + wrr + i2 * 16 + lgrp * 4 + q;
                    if (r < M) {
                        float v = acc[i2][j2][q] + bv;
                        if (HASR) v += res[(long)r * N + colc];
                        __builtin_nontemporal_store(v, &C[(long)r * N + colc]);
                    }
                }
            }
    }
}

// ---------------- attention stats: QK^T once, z-score in-register, write Z f16 ------
// 2 waves per task (6 heads each, S kept in registers); bidirectional partial-sum
// exchange via LDS; each wave z-scores its 6 register tiles and writes Z fragments.
// Z layout: [task][h][lane] f16x4 (fragment order) - 512B contiguous per (task,h).
__global__ __launch_bounds__(256) void k_stats(
        const half_t* __restrict__ qh, const half_t* __restrict__ kh,
        half_t* __restrict__ Z) {
    __shared__ f32x4 redv[2][2][64], redq[2][2][64];
    const int blk = (blockIdx.x & 7) * 338 + (blockIdx.x >> 3);   // 2704 = 8*338
    const int w = threadIdx.x >> 6, lane = threadIdx.x & 63;
    const int ti = w >> 1, hh2 = w & 1;
    const int task = blk * 2 + ti;                                 // 5408 tasks
    const int b = task / 169, r = task % 169;
    const int it = r / 13, jt = r % 13;
    const int lrow = lane & 15, lg = lane >> 4;
    const int i0 = it * 16, j0 = jt * 16;
    const int arow = min(i0 + lrow, Nn - 1);
    const int jr = min(j0 + lrow, Nn - 1);
    const int hbase = b * NH + hh2 * 6;

    float sAll[6][4];
    float sv[4] = {}, sq[4] = {};
#pragma unroll
    for (int h = 0; h < 6; h++) {
        const half_t* Qp = qh + ((long)(hbase + h) * Nn) * 64;
        const half_t* Kp = kh + ((long)(hbase + h) * Nn) * 64;
        half8 af0 = *(const half8*)&Qp[(long)arow * 64 + lg * 8];
        half8 af1 = *(const half8*)&Qp[(long)arow * 64 + 32 + lg * 8];
        half8 bf0 = *(const half8*)&Kp[(long)jr * 64 + lg * 8];
        half8 bf1 = *(const half8*)&Kp[(long)jr * 64 + 32 + lg * 8];
        f32x4 acc = {};
        acc = __builtin_amdgcn_mfma_f32_16x16x32_f16(af0, bf0, acc, 0, 0, 0);
        acc = __builtin_amdgcn_mfma_f32_16x16x32_f16(af1, bf1, acc, 0, 0, 0);
#pragma unroll
        for (int q = 0; q < 4; q++) {
            sAll[h][q] = acc[q];
            sv[q] += acc[q];
            sq[q] += acc[q] * acc[q];
        }
    }
    f32x4 a, b2;
#pragma unroll
    for (int q = 0; q < 4; q++) { a[q] = sv[q]; b2[q] = sq[q]; }
    redv[ti][hh2][lane] = a;
    redq[ti][hh2][lane] = b2;
    __syncthreads();
    f32x4 oa = redv[ti][hh2 ^ 1][lane], ob = redq[ti][hh2 ^ 1][lane];
    float mu[4], rs[4];
#pragma unroll
    for (int q = 0; q < 4; q++) {
        float svt = sv[q] + oa[q];
        float sqt = sq[q] + ob[q];
        mu[q] = svt * (1.f / NH);
        float var = (sqt - svt * mu[q]) * (1.f / (NH - 1));
        rs[q] = rsqrtf(var);
    }
    half_t* zp = Z + (((long)task * NH + hh2 * 6) * 64 + lane) * 4;
#pragma unroll
    for (int h = 0; h < 6; h++) {
        union { unsigned long long u; half_t hv[4]; } t;
#pragma unroll
        for (int q = 0; q < 4; q++)
            t.hv[q] = (half_t)((sAll[h][q] - mu[q]) * rs[q]);
        *(unsigned long long*)(zp + (long)h * 256) = t.u;
    }
}

// ---------------- attention per head: Z load + softmax + PV (no QK^T) ---------------
// 128 threads = 2 waves per (b,h,i-tile): wave0 jt 0..6, wave1 jt 7..12;
// max/sum exchanged via LDS; PV split by output d-tile (wave0 dt 0-1, wave1 dt 2-3).
__global__ __launch_bounds__(128) void k_attn2(
        const half_t* __restrict__ Z, const half_t* __restrict__ vt,
        half_t* __restrict__ o) {
    __shared__ half_t PB[16][232];
    __shared__ float xmx[2][16], xsm[2][16];
    const int tile = (blockIdx.x & 7) * 624 + (blockIdx.x >> 3);  // 4992 = 8*624
    const int bh = tile / 13, it = tile % 13;
    const int b = bh / NH, h = bh % NH;
    const int i0 = it * 16;
    const int tid = threadIdx.x;
    const int wv = tid >> 6, lane = tid & 63;
    const int lrow = lane & 15, lg = lane >> 4;
    const int jtbase = wv * 7;           // wv0: jt 0..6, wv1: jt 7..12
    const int njt = 7 - wv;              // 7 or 6

    if (wv == 0) {
        for (int idx = lane; idx < 128; idx += 64) {
            int rr = idx >> 3, u = idx & 7;
            *(unsigned int*)&PB[rr][208 + u * 2] = 0u;
        }
    }

    const long taskbase = (long)b * 169 + it * 13;
    float ez[7][4];
    float mx[4] = {-1e30f, -1e30f, -1e30f, -1e30f};
#pragma unroll
    for (int jj = 0; jj < 7; jj++) {
        if (jj < njt) {
            int jt = jtbase + jj;
            union { unsigned long long u; half_t hv[4]; } t;
            t.u = *(const unsigned long long*)(Z + (((taskbase + jt) * NH + h) * 64 + lane) * 4);
            bool joob = (jt * 16 + lrow) > Nn - 1;
#pragma unroll
            for (int q = 0; q < 4; q++) {
                float z = (float)t.hv[q];
                if (joob) z = -1e30f;
                ez[jj][q] = z;
                mx[q] = fmaxf(mx[q], z);
            }
        }
    }
#pragma unroll
    for (int st = 1; st <= 8; st <<= 1)
#pragma unroll
        for (int q = 0; q < 4; q++) mx[q] = fmaxf(mx[q], __shfl_xor(mx[q], st));
    if (lrow == 0) {
#pragma unroll
        for (int q = 0; q < 4; q++) xmx[wv][lg * 4 + q] = mx[q];
    }
    __syncthreads();
    float cmx[4];
#pragma unroll
    for (int q = 0; q < 4; q++)
        cmx[q] = fmaxf(xmx[0][lg * 4 + q], xmx[1][lg * 4 + q]);
    float sm[4] = {0.f, 0.f, 0.f, 0.f};
#pragma unroll
    for (int jj = 0; jj < 7; jj++) {
        if (jj < njt) {
#pragma unroll
            for (int q = 0; q < 4; q++) {
                float e = __expf(ez[jj][q] - cmx[q]);
                ez[jj][q] = e;
                sm[q] += e;
            }
        }
    }
#pragma unroll
    for (int st = 1; st <= 8; st <<= 1)
#pragma unroll
        for (int q = 0; q < 4; q++) sm[q] += __shfl_xor(sm[q], st);
    if (lrow == 0) {
#pragma unroll
        for (int q = 0; q < 4; q++) xsm[wv][lg * 4 + q] = sm[q];
    }
    __syncthreads();
    float inv[4];
#pragma unroll
    for (int q = 0; q < 4; q++)
        inv[q] = 1.f / (xsm[0][lg * 4 + q] + xsm[1][lg * 4 + q]);
#pragma unroll
    for (int jj = 0; jj < 7; jj++) {
        if (jj < njt) {
#pragma unroll
            for (int q = 0; q < 4; q++)
                PB[lg * 4 + q][(jtbase + jj) * 16 + lrow] = (half_t)(ez[jj][q] * inv[q]);
        }
    }
    __syncthreads();

    // PV: wave wv computes output d-tiles wv*2 .. wv*2+1
    const half_t* Vtp = vt + ((long)bh * 64) * 224;
#pragma unroll
    for (int dd = 0; dd < 2; dd++) {
        int dt = wv * 2 + dd;
        f32x4 oacc = {};
#pragma unroll
        for (int kt = 0; kt < 7; kt++) {
            half8 pa = *(const half8*)&PB[lrow][kt * 32 + lg * 8];
            half8 vb = *(const half8*)&Vtp[(long)(dt * 16 + lrow) * 224 + kt * 32 + lg * 8];
            oacc = __builtin_amdgcn_mfma_f32_16x16x32_f16(pa, vb, oacc, 0, 0, 0);
        }
#pragma unroll
        for (int q = 0; q < 4; q++) {
            int i = i0 + lg * 4 + q;
            if (i < Nn)
                o[((long)(b * Nn) + i) * INNERc + h * 64 + dt * 16 + lrow] = (half_t)oacc[q];
        }
    }
}

// ---------------- host launcher ----------------
extern "C" void kernel_launch(void* const* d_in, const int* in_sizes, int n_in,
                              void* d_out, int out_size, void* d_ws, size_t ws_size,
                              hipStream_t stream) {
    const float* img     = (const float*)d_in[0];
    const float* patch_g = (const float*)d_in[2];
    const float* patch_b = (const float*)d_in[3];
    const float* W_patch = (const float*)d_in[4];
    const float* b_patch = (const float*)d_in[5];
    const float* emb_g   = (const float*)d_in[6];
    const float* emb_b   = (const float*)d_in[7];
    const float* pos     = (const float*)d_in[8];
    const float* cls     = (const float*)d_in[9];
    const float* ln_g    = (const float*)d_in[10];
    const float* ln_b    = (const float*)d_in[11];
    const float* W_qkv   = (const float*)d_in[12];
    const float* W_out   = (const float*)d_in[13];
    const float* b_out   = (const float*)d_in[14];
    const float* fin_g   = (const float*)d_in[15];
    const float* fin_b   = (const float*)d_in[16];
    const float* W_head  = (const float*)d_in[17];
    const float* b_head  = (const float*)d_in[18];
    float* out = (float*)d_out;

    const long SZ_XD  = (long)Bc * Nn * Dd;            // 4,841,472
    const long SZ_HD  = (long)Bc * NH * Nn * DHd;      // 4,841,472
    const long SZ_VT  = (long)Bc * NH * 64 * 224;      // 5,505,024
    const long SZ_TMP = (long)Bc * NPc * Dd;
    const long SZ_Z   = (long)Bc * 169 * NH * 256;     // 16,613,376 halves (Z frags)

    float* x    = (float*)d_ws;
    float* tmp  = x + SZ_XD;
    half_t* xh       = (half_t*)(tmp + SZ_TMP);
    half_t* qhb      = xh + SZ_XD;
    half_t* khb      = qhb + SZ_HD;
    half_t* vtb      = khb + SZ_HD;
    half_t* Zb       = vtb + SZ_VT;
    half_t* clsh     = Zb + SZ_Z;                           // 32x768 f16
    half_t* wh_head  = clsh + 32 * Dd;                      // 1024x768 f16
    half_t* wt_patch = wh_head + 1024 * Dd;
    half_t* wt_qkv   = wt_patch + (long)Dd * Dd;
    half_t* wt_out   = wt_qkv + (long)DEPTHc * 3 * INNERc * Dd;

    // ---- weight prep ----
    hipLaunchKernelGGL(k_wprep, dim3(Dd / 32, Dd / 32, 1), dim3(32, 8), 0, stream,
                       W_patch, wt_patch, Dd, Dd);
    hipLaunchKernelGGL(k_wprep, dim3(3 * INNERc / 32, Dd / 32, DEPTHc), dim3(32, 8), 0, stream,
                       W_qkv, wt_qkv, Dd, 3 * INNERc);
    hipLaunchKernelGGL(k_wprep, dim3(Dd / 32, Dd / 32, DEPTHc), dim3(32, 8), 0, stream,
                       W_out, wt_out, Dd, Dd);
    hipLaunchKernelGGL(k_wprep_head, dim3(32, 24), dim3(32, 8), 0, stream,
                       W_head, wh_head);

    // 1. patchify + patch LN -> xh (f16)
    hipLaunchKernelGGL(k_patch_ln, dim3(Bc * NPc), dim3(256), 0, stream,
                       img, patch_g, patch_b, xh);
    // 2. patch GEMM (+b_patch) -> tmp fp32
    hipLaunchKernelGGL((k_hgemm<1, 0, float, 0>), dim3(6 * 49), dim3(256), 0, stream,
                       xh, wt_patch, b_patch, nullptr,
                       tmp, nullptr, nullptr, Bc * NPc, Dd, Dd);
    // 3. emb LN + cls concat + pos add -> x
    hipLaunchKernelGGL(k_embed, dim3(Bc * Nn), dim3(256), 0, stream,
                       tmp, cls, pos, emb_g, emb_b, x);

    const int Mrows = Bc * Nn;  // 6304
    for (int l = 0; l < DEPTHc; l++) {
        const float* g  = ln_g + (long)l * Dd;
        const float* bb = ln_b + (long)l * Dd;
        const half_t* Wq = wt_qkv + (long)l * 3 * INNERc * Dd;
        const half_t* Wo = wt_out + (long)l * Dd * Dd;
        const float* bo = b_out + (long)l * Dd;
        hipLaunchKernelGGL((k_ln<half_t>), dim3(Mrows), dim3(256), 0, stream,
                           x, g, bb, xh, (long)Dd, (long)Dd);
        // qkv GEMM; q/k head-major, V staged in LDS + written transposed coalesced
        hipLaunchKernelGGL((k_hgemm<0, 0, half_t, 1>), dim3(18 * 50), dim3(256), 0, stream,
                           xh, Wq, nullptr, nullptr,
                           qhb, khb, vtb, Mrows, 3 * INNERc, Dd);
        hipLaunchKernelGGL(k_stats, dim3(2704), dim3(256), 0, stream,
                           qhb, khb, Zb);
        hipLaunchKernelGGL(k_attn2, dim3(4992), dim3(128), 0, stream,
                           Zb, vtb, xh);
        hipLaunchKernelGGL((k_hgemm<1, 1, float, 0>), dim3(6 * 50), dim3(256), 0, stream,
                           xh, Wo, bo, x,
                           x, nullptr, nullptr, Mrows, Dd, Dd);
    }
    // final LN (cls rows only) -> clsh f16
    hipLaunchKernelGGL((k_ln<half_t>), dim3(Bc), dim3(256), 0, stream,
                       x, fin_g, fin_b, clsh, (long)Nn * Dd, (long)Dd);
    // head GEMM: f16 dot per (row,col)
    hipLaunchKernelGGL(k_head, dim3(128), dim3(256), 0, stream,
                       clsh, wh_head, b_head, out);
}

// Round 17
// 1565.280 us; speedup vs baseline: 2.3420x; 1.0128x over previous
//
#include <hip/hip_runtime.h>
#include <math.h>

// ---------------- problem constants ----------------
constexpr int Bc = 32, Cch = 3, Hh = 224, Ww = 224, Pp = 16;
constexpr int Dd = 768, NH = 12, DHd = 64, INNERc = 768;
constexpr int DEPTHc = 12, NCLS = 1000;
constexpr int NPc = 196, Nn = 197, PD = 768;
constexpr float EPSf = 1e-5f;

typedef _Float16 half_t;
typedef __attribute__((ext_vector_type(8))) _Float16 half8;
typedef __attribute__((ext_vector_type(4))) float f32x4;
typedef __attribute__((ext_vector_type(4))) unsigned int uint32x4;

// ---------------- reduction helpers ----------------
__device__ __forceinline__ float wave_red_sum(float v) {
#pragma unroll
    for (int m = 32; m; m >>= 1) v += __shfl_xor(v, m);
    return v;
}

__device__ __forceinline__ void block_red2(float& s, float& s2, float* red) {
    s = wave_red_sum(s);
    s2 = wave_red_sum(s2);
    int wid = threadIdx.x >> 6, lane = threadIdx.x & 63;
    if (lane == 0) { red[wid] = s; red[4 + wid] = s2; }
    __syncthreads();
    s = red[0] + red[1] + red[2] + red[3];
    s2 = red[4] + red[5] + red[6] + red[7];
}

// ---------------- patchify + patch LN -> f16 ----------------
__global__ __launch_bounds__(256) void k_patch_ln(
        const float* __restrict__ img, const float* __restrict__ g,
        const float* __restrict__ bb, half_t* __restrict__ out) {
    int pid = blockIdx.x;
    int b = pid / NPc, n = pid % NPc;
    int ph = n / 14, pw = n % 14;
    int t = threadIdx.x;
    __shared__ float red[8];
    float v[3];
#pragma unroll
    for (int i = 0; i < 3; i++) {
        int d = t + i * 256;
        int c = d % 3, q = (d / 3) & 15, p = d / 48;
        v[i] = img[((long)(b * Cch + c) * Hh + ph * Pp + p) * Ww + pw * Pp + q];
    }
    float s = v[0] + v[1] + v[2];
    float s2 = v[0] * v[0] + v[1] * v[1] + v[2] * v[2];
    block_red2(s, s2, red);
    float mu = s * (1.f / PD);
    float var = s2 * (1.f / PD) - mu * mu;
    float r = rsqrtf(var + EPSf);
#pragma unroll
    for (int i = 0; i < 3; i++) {
        int d = t + i * 256;
        out[(long)pid * PD + d] = (half_t)((v[i] - mu) * r * g[d] + bb[d]);
    }
}

// ---------------- row LayerNorm (768 wide), templated output ----------------
template <typename T>
__global__ __launch_bounds__(256) void k_ln(
        const float* __restrict__ in, const float* __restrict__ g,
        const float* __restrict__ bb, T* __restrict__ out,
        long in_stride, long out_stride) {
    long row = blockIdx.x;
    const float* ip = in + row * in_stride;
    T* op = out + row * out_stride;
    int t = threadIdx.x;
    __shared__ float red[8];
    float v[3];
#pragma unroll
    for (int i = 0; i < 3; i++) v[i] = ip[t + i * 256];
    float s = v[0] + v[1] + v[2];
    float s2 = v[0] * v[0] + v[1] * v[1] + v[2] * v[2];
    block_red2(s, s2, red);
    float mu = s * (1.f / Dd);
    float var = s2 * (1.f / Dd) - mu * mu;
    float r = rsqrtf(var + EPSf);
#pragma unroll
    for (int i = 0; i < 3; i++) {
        int d = t + i * 256;
        op[d] = (T)((v[i] - mu) * r * g[d] + bb[d]);
    }
}

// ---------------- embed assemble: LN(tmp)+pos, cls+pos ----------------
__global__ __launch_bounds__(256) void k_embed(
        const float* __restrict__ tmp, const float* __restrict__ cls,
        const float* __restrict__ pos, const float* __restrict__ g,
        const float* __restrict__ bb, float* __restrict__ x) {
    int pid = blockIdx.x;
    int b = pid / Nn, n = pid % Nn;
    int t = threadIdx.x;
    float* xp = x + (long)pid * Dd;
    if (n == 0) {
#pragma unroll
        for (int i = 0; i < 3; i++) {
            int d = t + i * 256;
            xp[d] = cls[d] + pos[d];
        }
        return;
    }
    const float* ip = tmp + (long)(b * NPc + n - 1) * Dd;
    __shared__ float red[8];
    float v[3];
#pragma unroll
    for (int i = 0; i < 3; i++) v[i] = ip[t + i * 256];
    float s = v[0] + v[1] + v[2];
    float s2 = v[0] * v[0] + v[1] * v[1] + v[2] * v[2];
    block_red2(s, s2, red);
    float mu = s * (1.f / Dd);
    float var = s2 * (1.f / Dd) - mu * mu;
    float r = rsqrtf(var + EPSf);
#pragma unroll
    for (int i = 0; i < 3; i++) {
        int d = t + i * 256;
        xp[d] = (v[i] - mu) * r * g[d] + bb[d] + pos[(long)n * Dd + d];
    }
}

// ---------------- weight prep: fp32 W[K][N] -> f16 Wt[N][K] ----------------
__global__ __launch_bounds__(256) void k_wprep(
        const float* __restrict__ W, half_t* __restrict__ Wt, int K, int N) {
    W += (long)blockIdx.z * K * N;
    Wt += (long)blockIdx.z * K * N;
    __shared__ float tile[32][33];
    int n = blockIdx.x * 32 + threadIdx.x;
    int k0 = blockIdx.y * 32;
#pragma unroll
    for (int i = 0; i < 4; i++)
        tile[threadIdx.y + i * 8][threadIdx.x] = W[(long)(k0 + threadIdx.y + i * 8) * N + n];
    __syncthreads();
    int kk = k0 + threadIdx.x;
#pragma unroll
    for (int i = 0; i < 4; i++)
        Wt[(long)(blockIdx.x * 32 + threadIdx.y + i * 8) * K + kk] =
            (half_t)tile[threadIdx.x][threadIdx.y + i * 8];
}

// ---------------- head weight prep: fp32 [768][1000] -> f16 [1024][768] (pad 0) --------
__global__ __launch_bounds__(256) void k_wprep_head(
        const float* __restrict__ W, half_t* __restrict__ Wt) {
    __shared__ float tile[32][33];
    int n = blockIdx.x * 32 + threadIdx.x;
    int k0 = blockIdx.y * 32;
#pragma unroll
    for (int i = 0; i < 4; i++)
        tile[threadIdx.y + i * 8][threadIdx.x] =
            (n < NCLS) ? W[(long)(k0 + threadIdx.y + i * 8) * NCLS + n] : 0.f;
    __syncthreads();
    int kk = k0 + threadIdx.x;
#pragma unroll
    for (int i = 0; i < 4; i++)
        Wt[(long)(blockIdx.x * 32 + threadIdx.y + i * 8) * Dd + kk] =
            (half_t)tile[threadIdx.x][threadIdx.y + i * 8];
}

// ---------------- head GEMM: one thread per (row,col), f16 dot ----------------
__global__ __launch_bounds__(256) void k_head(
        const half_t* __restrict__ Ah, const half_t* __restrict__ Wh,
        const float* __restrict__ bias, float* __restrict__ out) {
    int idx = blockIdx.x * 256 + threadIdx.x;
    int row = idx >> 10, col = idx & 1023;
    if (col >= NCLS) return;
    const half_t* ap = Ah + (long)row * Dd;
    const half_t* wp = Wh + (long)col * Dd;
    float acc = 0.f;
#pragma unroll
    for (int k = 0; k < 96; k++) {
        half8 a = *(const half8*)&ap[k * 8];
        half8 w = *(const half8*)&wp[k * 8];
#pragma unroll
        for (int u = 0; u < 8; u++) acc += (float)a[u] * (float)w[u];
    }
    out[(long)row * NCLS + col] = acc + bias[col];
}

// ---------------- f16 MFMA GEMM ----------------
// Staging via global_load_lds width=16 (m97 structure): LDS dest linear
// (wave-uniform base + lane*16); global SOURCE pre-swizzled by chunk^(row&7)
// so the existing XOR-swizzled ds_read fragment path is unchanged (m173).
// OMODE=1 (qkv): C=q, C1=k head-major [b,h,n,64]; V third (n0>=1536) staged
//   TRANSPOSED in LDS then written lane-coalesced into Vt [b,h,64,224].
__device__ __forceinline__ half8 lds_frag(const uint32x4 (*L)[8], int row, int slot) {
    union { uint32x4 u; half8 h; } t;
    t.u = L[row][slot];
    return t.h;
}

__device__ __forceinline__ void gload16(const half_t* g, uint32x4* l) {
    __builtin_amdgcn_global_load_lds(
        (const __attribute__((address_space(1))) unsigned int*)g,
        (__attribute__((address_space(3))) unsigned int*)l,
        16, 0, 0);
}

template <int HASB, int HASR, typename CT, int OMODE>
__global__ __launch_bounds__(256, 2) void k_hgemm(
        const half_t* __restrict__ A, const half_t* __restrict__ Bt,
        const float* __restrict__ bias, const float* __restrict__ res,
        CT* __restrict__ C, CT* __restrict__ C1, half_t* __restrict__ Vt,
        int M, int N, int K) {
    __shared__ uint32x4 smem[2176];   // A[1024] | B[1024]; epilogue aliases half Cs
    uint32x4 (*As)[8] = (uint32x4(*)[8])smem;
    uint32x4 (*Bs)[8] = (uint32x4(*)[8])(smem + 1024);
    const int tid = threadIdx.x;
    const int nwg = gridDim.x;
    const int q8 = nwg >> 3, r8 = nwg & 7;
    const int xc = blockIdx.x & 7, oo = blockIdx.x >> 3;
    const int tile = (xc < r8 ? xc * (q8 + 1) : r8 * (q8 + 1) + (xc - r8) * q8) + oo;
    const int gx = N >> 7;
    const int n0 = (tile % gx) * 128, m0 = (tile / gx) * 128;
    const int lane = tid & 63, w = tid >> 6;
    const int wrr = (w >> 1) * 64, wcc = (w & 1) * 64;
    const int lrow = lane & 15, lgrp = lane >> 4;

    // staging: each wave owns 32 rows (4 calls x 8 rows); lane l covers
    // row (l>>3), slot (l&7) of the 1KB span. Source chunk pre-swizzled.
    int ldsOff[4];
    long gsA[4], gsB[4];
#pragma unroll
    for (int c = 0; c < 4; ++c) {
        int r = w * 32 + c * 8 + (lane >> 3);
        int chunk = (lane & 7) ^ (r & 7);
        ldsOff[c] = (w * 32 + c * 8) * 8;
        gsA[c] = (long)min(m0 + r, M - 1) * K + chunk * 8;
        gsB[c] = (long)(n0 + r) * K + chunk * 8;
    }

    f32x4 acc[4][4] = {};

#define STAGE(k0)                                         \
    {                                                     \
        _Pragma("unroll")                                 \
        for (int c = 0; c < 4; ++c) {                     \
            gload16(A + gsA[c] + (k0), smem + ldsOff[c]); \
            gload16(Bt + gsB[c] + (k0), smem + 1024 + ldsOff[c]); \
        }                                                 \
    }

    STAGE(0);
    __syncthreads();

    const int nst = K >> 6;
    for (int t = 0; t < nst; ++t) {
#pragma unroll
        for (int kh = 0; kh < 2; ++kh) {
            half8 af[4], bf[4];
#pragma unroll
            for (int i2 = 0; i2 < 4; ++i2) {
                int m = wrr + i2 * 16 + lrow;
                af[i2] = lds_frag(As, m, (kh * 4 + lgrp) ^ (m & 7));
                int n = wcc + i2 * 16 + lrow;
                bf[i2] = lds_frag(Bs, n, (kh * 4 + lgrp) ^ (n & 7));
            }
#pragma unroll
            for (int i2 = 0; i2 < 4; ++i2)
#pragma unroll
                for (int j2 = 0; j2 < 4; ++j2)
                    acc[i2][j2] = __builtin_amdgcn_mfma_f32_16x16x32_f16(af[i2], bf[j2], acc[i2][j2], 0, 0, 0);
        }
        if (t + 1 < nst) {
            __syncthreads();            // all reads of current tile done
            STAGE((t + 1) << 6);        // async global->LDS
            __syncthreads();            // loads complete (vmcnt drained)
        }
    }
#undef STAGE

    if constexpr (sizeof(CT) == 2) {
        if constexpr (OMODE == 1) {
            if (n0 >= 1536) {
                // V third: stage TRANSPOSED in LDS (Cs[col][token], stride 136),
                // then lane-coalesced scalar stores (consecutive lanes = consecutive nn).
                __syncthreads();
                half_t* Cs = (half_t*)smem;
#pragma unroll
                for (int i2 = 0; i2 < 4; ++i2)
#pragma unroll
                    for (int j2 = 0; j2 < 4; ++j2) {
                        int colc = wcc + j2 * 16 + lrow;
#pragma unroll
                        for (int q = 0; q < 4; ++q) {
                            int r = wrr + i2 * 16 + lgrp * 4 + q;
                            Cs[colc * 136 + r] = (half_t)acc[i2][j2][q];
                        }
                    }
                __syncthreads();
                const int rr = tid & 127;      // token offset (lane-consecutive)
                const int cbase = (tid >> 7) * 64;
                int token = m0 + rr;
                bool ok = token < M;
                int b = 0, nn = 0;
                if (ok) { b = token / Nn; nn = token - b * Nn; }
#pragma unroll
                for (int cc = 0; cc < 64; ++cc) {
                    int c = cbase + cc;
                    int rem = n0 + c - 1536;
                    int h = rem >> 6, d = rem & 63;
                    if (ok)
                        Vt[((long)(b * NH + h) * 64 + d) * 224 + nn] = Cs[c * 136 + rr];
                }
                return;
            }
        }
        __syncthreads();
        half_t* Cs = (half_t*)smem;
#pragma unroll
        for (int i2 = 0; i2 < 4; ++i2)
#pragma unroll
            for (int j2 = 0; j2 < 4; ++j2) {
                int colc = wcc + j2 * 16 + lrow;
                float bv = HASB ? bias[n0 + colc] : 0.f;
#pragma unroll
                for (int q = 0; q < 4; ++q) {
                    int r = wrr + i2 * 16 + lgrp * 4 + q;
                    Cs[r * 136 + colc] = (half_t)(acc[i2][j2][q] + bv);
                }
            }
        __syncthreads();
#pragma unroll
        for (int it = 0; it < 8; ++it) {
            int idx = tid + it * 256;
            int row = idx >> 4, cu = idx & 15;
            int token = m0 + row;
            if (token < M) {
                uint32x4 val = *(const uint32x4*)(Cs + row * 136 + cu * 8);
                if constexpr (OMODE == 1) {
                    int gc = n0 + cu * 8;
                    int which = gc >= 768 ? 1 : 0;
                    int rem = gc - which * 768;
                    int h = rem >> 6, d = rem & 63;
                    int b = token / Nn, nn = token - b * Nn;
                    CT* dst = (which == 0 ? C : C1);
                    __builtin_nontemporal_store(val,
                        (uint32x4*)(dst + (((long)(b * NH + h) * Nn + nn) << 6) + d));
                } else {
                    __builtin_nontemporal_store(val,
                        (uint32x4*)(C + (long)token * N + n0 + cu * 8));
                }
            }
        }
    } else {
#pragma unroll
        for (int i2 = 0; i2 < 4; ++i2)
#pragma unroll
            for (int j2 = 0; j2 < 4; ++j2) {
                int colc = n0 + wcc + j2 * 16 + lrow;
                float bv = HASB ? bias[colc] : 0.f;
#pragma unroll
                for (int q = 0; q < 4; ++q) {
                    int r = m0 + wrr + i2 * 16 + lgrp * 4 + q;
                    if (r < M) {
                        float v = acc[i2][j2][q] + bv;
                        if (HASR) v += res[(long)r * N + colc];
                        __builtin_nontemporal_store(v, &C[(long)r * N + colc]);
                    }
                }
            }
    }
}

// ---------------- attention stats: QK^T once, z-score in-register, write Z f16 ------
// 4 waves per task (3 heads each, S kept in registers); partial sums exchanged
// via LDS in fixed order (deterministic, identical on all waves); each wave
// z-scores its 3 register tiles and writes Z fragments.
// Z layout: [task][h][lane] f16x4 (fragment order) - 512B contiguous per (task,h).
__global__ __launch_bounds__(256) void k_stats(
        const half_t* __restrict__ qh, const half_t* __restrict__ kh,
        half_t* __restrict__ Z) {
    __shared__ f32x4 redv[4][64], redq[4][64];
    const int task = (blockIdx.x & 7) * 676 + (blockIdx.x >> 3);   // 5408 = 8*676
    const int w = threadIdx.x >> 6, lane = threadIdx.x & 63;
    const int b = task / 169, r = task % 169;
    const int it = r / 13, jt = r % 13;
    const int lrow = lane & 15, lg = lane >> 4;
    const int i0 = it * 16, j0 = jt * 16;
    const int arow = min(i0 + lrow, Nn - 1);
    const int jr = min(j0 + lrow, Nn - 1);
    const int hbase = b * NH + w * 3;

    float sAll[3][4];
    float sv[4] = {}, sq[4] = {};
#pragma unroll
    for (int h = 0; h < 3; h++) {
        const half_t* Qp = qh + ((long)(hbase + h) * Nn) * 64;
        const half_t* Kp = kh + ((long)(hbase + h) * Nn) * 64;
        half8 af0 = *(const half8*)&Qp[(long)arow * 64 + lg * 8];
        half8 af1 = *(const half8*)&Qp[(long)arow * 64 + 32 + lg * 8];
        half8 bf0 = *(const half8*)&Kp[(long)jr * 64 + lg * 8];
        half8 bf1 = *(const half8*)&Kp[(long)jr * 64 + 32 + lg * 8];
        f32x4 acc = {};
        acc = __builtin_amdgcn_mfma_f32_16x16x32_f16(af0, bf0, acc, 0, 0, 0);
        acc = __builtin_amdgcn_mfma_f32_16x16x32_f16(af1, bf1, acc, 0, 0, 0);
#pragma unroll
        for (int q = 0; q < 4; q++) {
            sAll[h][q] = acc[q];
            sv[q] += acc[q];
            sq[q] += acc[q] * acc[q];
        }
    }
    f32x4 a, b2;
#pragma unroll
    for (int q = 0; q < 4; q++) { a[q] = sv[q]; b2[q] = sq[q]; }
    redv[w][lane] = a;
    redq[w][lane] = b2;
    __syncthreads();
    f32x4 v0 = redv[0][lane], v1 = redv[1][lane], v2 = redv[2][lane], v3 = redv[3][lane];
    f32x4 q0 = redq[0][lane], q1 = redq[1][lane], q2 = redq[2][lane], q3 = redq[3][lane];
    float mu[4], rs[4];
#pragma unroll
    for (int q = 0; q < 4; q++) {
        float svt = (v0[q] + v1[q]) + (v2[q] + v3[q]);
        float sqt = (q0[q] + q1[q]) + (q2[q] + q3[q]);
        mu[q] = svt * (1.f / NH);
        float var = (sqt - svt * mu[q]) * (1.f / (NH - 1));
        rs[q] = rsqrtf(var);
    }
    half_t* zp = Z + (((long)task * NH + w * 3) * 64 + lane) * 4;
#pragma unroll
    for (int h = 0; h < 3; h++) {
        union { unsigned long long u; half_t hv[4]; } t;
#pragma unroll
        for (int q = 0; q < 4; q++)
            t.hv[q] = (half_t)((sAll[h][q] - mu[q]) * rs[q]);
        *(unsigned long long*)(zp + (long)h * 256) = t.u;
    }
}

// ---------------- attention per head: Z load + softmax + PV (no QK^T) ---------------
// 128 threads = 2 waves per (b,h,i-tile): wave0 jt 0..6, wave1 jt 7..12;
// max/sum exchanged via LDS; PV split by output d-tile (wave0 dt 0-1, wave1 dt 2-3).
__global__ __launch_bounds__(128) void k_attn2(
        const half_t* __restrict__ Z, const half_t* __restrict__ vt,
        half_t* __restrict__ o) {
    __shared__ half_t PB[16][232];
    __shared__ float xmx[2][16], xsm[2][16];
    const int tile = (blockIdx.x & 7) * 624 + (blockIdx.x >> 3);  // 4992 = 8*624
    const int bh = tile / 13, it = tile % 13;
    const int b = bh / NH, h = bh % NH;
    const int i0 = it * 16;
    const int tid = threadIdx.x;
    const int wv = tid >> 6, lane = tid & 63;
    const int lrow = lane & 15, lg = lane >> 4;
    const int jtbase = wv * 7;           // wv0: jt 0..6, wv1: jt 7..12
    const int njt = 7 - wv;              // 7 or 6

    if (wv == 0) {
        for (int idx = lane; idx < 128; idx += 64) {
            int rr = idx >> 3, u = idx & 7;
            *(unsigned int*)&PB[rr][208 + u * 2] = 0u;
        }
    }

    const long taskbase = (long)b * 169 + it * 13;
    float ez[7][4];
    float mx[4] = {-1e30f, -1e30f, -1e30f, -1e30f};
#pragma unroll
    for (int jj = 0; jj < 7; jj++) {
        if (jj < njt) {
            int jt = jtbase + jj;
            union { unsigned long long u; half_t hv[4]; } t;
            t.u = *(const unsigned long long*)(Z + (((taskbase + jt) * NH + h) * 64 + lane) * 4);
            bool joob = (jt * 16 + lrow) > Nn - 1;
#pragma unroll
            for (int q = 0; q < 4; q++) {
                float z = (float)t.hv[q];
                if (joob) z = -1e30f;
                ez[jj][q] = z;
                mx[q] = fmaxf(mx[q], z);
            }
        }
    }
#pragma unroll
    for (int st = 1; st <= 8; st <<= 1)
#pragma unroll
        for (int q = 0; q < 4; q++) mx[q] = fmaxf(mx[q], __shfl_xor(mx[q], st));
    if (lrow == 0) {
#pragma unroll
        for (int q = 0; q < 4; q++) xmx[wv][lg * 4 + q] = mx[q];
    }
    __syncthreads();
    float cmx[4];
#pragma unroll
    for (int q = 0; q < 4; q++)
        cmx[q] = fmaxf(xmx[0][lg * 4 + q], xmx[1][lg * 4 + q]);
    float sm[4] = {0.f, 0.f, 0.f, 0.f};
#pragma unroll
    for (int jj = 0; jj < 7; jj++) {
        if (jj < njt) {
#pragma unroll
            for (int q = 0; q < 4; q++) {
                float e = __expf(ez[jj][q] - cmx[q]);
                ez[jj][q] = e;
                sm[q] += e;
            }
        }
    }
#pragma unroll
    for (int st = 1; st <= 8; st <<= 1)
#pragma unroll
        for (int q = 0; q < 4; q++) sm[q] += __shfl_xor(sm[q], st);
    if (lrow == 0) {
#pragma unroll
        for (int q = 0; q < 4; q++) xsm[wv][lg * 4 + q] = sm[q];
    }
    __syncthreads();
    float inv[4];
#pragma unroll
    for (int q = 0; q < 4; q++)
        inv[q] = 1.f / (xsm[0][lg * 4 + q] + xsm[1][lg * 4 + q]);
#pragma unroll
    for (int jj = 0; jj < 7; jj++) {
        if (jj < njt) {
#pragma unroll
            for (int q = 0; q < 4; q++)
                PB[lg * 4 + q][(jtbase + jj) * 16 + lrow] = (half_t)(ez[jj][q] * inv[q]);
        }
    }
    __syncthreads();

    // PV: wave wv computes output d-tiles wv*2 .. wv*2+1
    const half_t* Vtp = vt + ((long)bh * 64) * 224;
#pragma unroll
    for (int dd = 0; dd < 2; dd++) {
        int dt = wv * 2 + dd;
        f32x4 oacc = {};
#pragma unroll
        for (int kt = 0; kt < 7; kt++) {
            half8 pa = *(const half8*)&PB[lrow][kt * 32 + lg * 8];
            half8 vb = *(const half8*)&Vtp[(long)(dt * 16 + lrow) * 224 + kt * 32 + lg * 8];
            oacc = __builtin_amdgcn_mfma_f32_16x16x32_f16(pa, vb, oacc, 0, 0, 0);
        }
#pragma unroll
        for (int q = 0; q < 4; q++) {
            int i = i0 + lg * 4 + q;
            if (i < Nn)
                o[((long)(b * Nn) + i) * INNERc + h * 64 + dt * 16 + lrow] = (half_t)oacc[q];
        }
    }
}

// ---------------- host launcher ----------------
extern "C" void kernel_launch(void* const* d_in, const int* in_sizes, int n_in,
                              void* d_out, int out_size, void* d_ws, size_t ws_size,
                              hipStream_t stream) {
    const float* img     = (const float*)d_in[0];
    const float* patch_g = (const float*)d_in[2];
    const float* patch_b = (const float*)d_in[3];
    const float* W_patch = (const float*)d_in[4];
    const float* b_patch = (const float*)d_in[5];
    const float* emb_g   = (const float*)d_in[6];
    const float* emb_b   = (const float*)d_in[7];
    const float* pos     = (const float*)d_in[8];
    const float* cls     = (const float*)d_in[9];
    const float* ln_g    = (const float*)d_in[10];
    const float* ln_b    = (const float*)d_in[11];
    const float* W_qkv   = (const float*)d_in[12];
    const float* W_out   = (const float*)d_in[13];
    const float* b_out   = (const float*)d_in[14];
    const float* fin_g   = (const float*)d_in[15];
    const float* fin_b   = (const float*)d_in[16];
    const float* W_head  = (const float*)d_in[17];
    const float* b_head  = (const float*)d_in[18];
    float* out = (float*)d_out;

    const long SZ_XD  = (long)Bc * Nn * Dd;            // 4,841,472
    const long SZ_HD  = (long)Bc * NH * Nn * DHd;      // 4,841,472
    const long SZ_VT  = (long)Bc * NH * 64 * 224;      // 5,505,024
    const long SZ_TMP = (long)Bc * NPc * Dd;
    const long SZ_Z   = (long)Bc * 169 * NH * 256;     // 16,613,376 halves (Z frags)

    float* x    = (float*)d_ws;
    float* tmp  = x + SZ_XD;
    half_t* xh       = (half_t*)(tmp + SZ_TMP);
    half_t* qhb      = xh + SZ_XD;
    half_t* khb      = qhb + SZ_HD;
    half_t* vtb      = khb + SZ_HD;
    half_t* Zb       = vtb + SZ_VT;
    half_t* clsh     = Zb + SZ_Z;                           // 32x768 f16
    half_t* wh_head  = clsh + 32 * Dd;                      // 1024x768 f16
    half_t* wt_patch = wh_head + 1024 * Dd;
    half_t* wt_qkv   = wt_patch + (long)Dd * Dd;
    half_t* wt_out   = wt_qkv + (long)DEPTHc * 3 * INNERc * Dd;

    // ---- weight prep ----
    hipLaunchKernelGGL(k_wprep, dim3(Dd / 32, Dd / 32, 1), dim3(32, 8), 0, stream,
                       W_patch, wt_patch, Dd, Dd);
    hipLaunchKernelGGL(k_wprep, dim3(3 * INNERc / 32, Dd / 32, DEPTHc), dim3(32, 8), 0, stream,
                       W_qkv, wt_qkv, Dd, 3 * INNERc);
    hipLaunchKernelGGL(k_wprep, dim3(Dd / 32, Dd / 32, DEPTHc), dim3(32, 8), 0, stream,
                       W_out, wt_out, Dd, Dd);
    hipLaunchKernelGGL(k_wprep_head, dim3(32, 24), dim3(32, 8), 0, stream,
                       W_head, wh_head);

    // 1. patchify + patch LN -> xh (f16)
    hipLaunchKernelGGL(k_patch_ln, dim3(Bc * NPc), dim3(256), 0, stream,
                       img, patch_g, patch_b, xh);
    // 2. patch GEMM (+b_patch) -> tmp fp32
    hipLaunchKernelGGL((k_hgemm<1, 0, float, 0>), dim3(6 * 49), dim3(256), 0, stream,
                       xh, wt_patch, b_patch, nullptr,
                       tmp, nullptr, nullptr, Bc * NPc, Dd, Dd);
    // 3. emb LN + cls concat + pos add -> x
    hipLaunchKernelGGL(k_embed, dim3(Bc * Nn), dim3(256), 0, stream,
                       tmp, cls, pos, emb_g, emb_b, x);

    const int Mrows = Bc * Nn;  // 6304
    for (int l = 0; l < DEPTHc; l++) {
        const float* g  = ln_g + (long)l * Dd;
        const float* bb = ln_b + (long)l * Dd;
        const half_t* Wq = wt_qkv + (long)l * 3 * INNERc * Dd;
        const half_t* Wo = wt_out + (long)l * Dd * Dd;
        const float* bo = b_out + (long)l * Dd;
        hipLaunchKernelGGL((k_ln<half_t>), dim3(Mrows), dim3(256), 0, stream,
                           x, g, bb, xh, (long)Dd, (long)Dd);
        // qkv GEMM; q/k head-major, V staged in LDS + written transposed coalesced
        hipLaunchKernelGGL((k_hgemm<0, 0, half_t, 1>), dim3(18 * 50), dim3(256), 0, stream,
                           xh, Wq, nullptr, nullptr,
                           qhb, khb, vtb, Mrows, 3 * INNERc, Dd);
        hipLaunchKernelGGL(k_stats, dim3(5408), dim3(256), 0, stream,
                           qhb, khb, Zb);
        hipLaunchKernelGGL(k_attn2, dim3(4992), dim3(128), 0, stream,
                           Zb, vtb, xh);
        hipLaunchKernelGGL((k_hgemm<1, 1, float, 0>), dim3(6 * 50), dim3(256), 0, stream,
                           xh, Wo, bo, x,
                           x, nullptr, nullptr, Mrows, Dd, Dd);
    }
    // final LN (cls rows only) -> clsh f16
    hipLaunchKernelGGL((k_ln<half_t>), dim3(Bc), dim3(256), 0, stream,
                       x, fin_g, fin_b, clsh, (long)Nn * Dd, (long)Dd);
    // head GEMM: f16 dot per (row,col)
    hipLaunchKernelGGL(k_head, dim3(128), dim3(256), 0, stream,
                       clsh, wh_head, b_head, out);
}